// Round 6
// baseline (409.082 us; speedup 1.0000x reference)
//
#include <hip/hip_runtime.h>
#include <math.h>

// n=2, C=288, h=w=64 -> hw=4096; kv stride 2 -> 32x32 -> pkv=1024; M=9 heads, d=32
#define NB     2
#define CDIM   288
#define HW     4096
#define PKV    1024
#define MHEAD  9
#define DHEAD  32

typedef __attribute__((ext_vector_type(8))) short bf16x8;
typedef __attribute__((ext_vector_type(4))) float f32x4;

#if __has_builtin(__builtin_amdgcn_exp2f)
#define EXP2(x) __builtin_amdgcn_exp2f(x)
#else
#define EXP2(x) exp2f(x)
#endif

__device__ inline unsigned short f2bf(float x) {
    unsigned int u = __float_as_uint(x);
    u = (u + 0x7fffu + ((u >> 16) & 1u)) >> 16;
    return (unsigned short)u;
}

// ---------------------------------------------------------------------------
// prep: fused xtransF (float4) + wcvtF + meanx.
__global__ __launch_bounds__(256) void prep(const float* __restrict__ X,
        const float* __restrict__ Wq, const float* __restrict__ Wk,
        const float* __restrict__ Wv, const float* __restrict__ Wproj,
        unsigned short* __restrict__ XF, unsigned short* __restrict__ WFq,
        unsigned short* __restrict__ WFk, unsigned short* __restrict__ WFv,
        unsigned short* __restrict__ WFp, float* __restrict__ MX) {
    __shared__ float t32[32][133];
    __shared__ float red[4];
    int b = blockIdx.x;
    int tid = threadIdx.x;
    if (b < 576) {
        int bx = b % 32, by = (b / 32) % 9, n = b / 288;
        int j0 = bx * 128, c0 = by * 32;
        int c = tid >> 3, f = tid & 7;
        const float* src = &X[((size_t)n * CDIM + c0 + c) * HW + j0];
#pragma unroll
        for (int l = 0; l < 4; ++l) {
            float4 v = *(const float4*)&src[(f + l * 8) * 4];
            *(float4*)&t32[c][(f + l * 8) * 4] = v;
        }
        __syncthreads();
        int cc = c0 >> 5;
#pragma unroll
        for (int l = 0; l < 4; ++l) {
            int g = l * 256 + tid;
            int s = g >> 7;
            int w = g & 127;
            int lane = w >> 1, e0 = (w & 1) * 4;
            int jl = s * 16 + (lane & 15);
            int cb = (lane >> 4) * 8 + e0;
            unsigned int w0 = f2bf(t32[cb + 0][jl]) | ((unsigned int)f2bf(t32[cb + 1][jl]) << 16);
            unsigned int w1 = f2bf(t32[cb + 2][jl]) | ((unsigned int)f2bf(t32[cb + 3][jl]) << 16);
            int jt = (j0 >> 4) + s;
            unsigned short* O = XF + (size_t)n * HW * CDIM + ((size_t)jt * 9 + cc) * 512 + lane * 8 + e0;
            uint2 pk = { w0, w1 };
            *(uint2*)O = pk;
        }
    } else if (b < 738) {
        int t = b - 576;
        int sub = tid >> 6, lane = tid & 63;
        int ot = t / 9, cc = t % 9;
        const float* W = (sub == 0) ? Wq : (sub == 1) ? Wk : (sub == 2) ? Wv : Wproj;
        unsigned short* O = ((sub == 0) ? WFq : (sub == 1) ? WFk : (sub == 2) ? WFv : WFp)
                            + (size_t)t * 512;
        int o  = ot * 16 + (lane & 15);
        int c0 = cc * 32 + (lane >> 4) * 8;
        const float* src = W + (size_t)o * CDIM + c0;
        float4 f0 = *(const float4*)src, f1 = *(const float4*)(src + 4);
        unsigned int v0 = f2bf(f0.x) | ((unsigned int)f2bf(f0.y) << 16);
        unsigned int v1 = f2bf(f0.z) | ((unsigned int)f2bf(f0.w) << 16);
        unsigned int v2 = f2bf(f1.x) | ((unsigned int)f2bf(f1.y) << 16);
        unsigned int v3 = f2bf(f1.z) | ((unsigned int)f2bf(f1.w) << 16);
        uint4 pk = { v0, v1, v2, v3 };
        *(uint4*)(O + lane * 8) = pk;
    } else {
        int bid = b - 738;
        const float* xr = X + (size_t)bid * HW;
        float s = 0.f;
        for (int j = tid; j < HW; j += 256) s += xr[j];
        for (int off = 32; off > 0; off >>= 1) s += __shfl_xor(s, off, 64);
        if ((tid & 63) == 0) red[tid >> 6] = s;
        __syncthreads();
        if (tid == 0) MX[bid] = (red[0] + red[1] + red[2] + red[3]) * (1.f / 4096.f);
    }
}

// ---------------------------------------------------------------------------
// mid: fused pff + mixw2 + qkv.  Qf pre-scaled by log2(e).
__global__ __launch_bounds__(256) void mid(
        const float* __restrict__ Wx, const float* __restrict__ Wy,
        unsigned short* __restrict__ FXb, unsigned short* __restrict__ FYb,
        const float* __restrict__ Wq, const float* __restrict__ MX,
        const float* __restrict__ Wc, const float* __restrict__ bc,
        float* __restrict__ MIXW,
        const unsigned short* __restrict__ WFq, const unsigned short* __restrict__ WFk,
        const unsigned short* __restrict__ WFv, const unsigned short* __restrict__ XF,
        unsigned short* __restrict__ Qf, unsigned short* __restrict__ KF,
        unsigned short* __restrict__ VF) {
    __shared__ float emb[144];
    __shared__ float ctx_s[NB * CDIM];
    __shared__ float lg[18];
    __shared__ __attribute__((aligned(16))) unsigned short tr[4][32][40];
    int b = blockIdx.x;
    int tid = threadIdx.x;

    if (b < 252) {
        int axis = b / 126;
        int dif  = b % 126;
        float diff = (float)(dif - 62);
        if (tid < 72) {
            float dm = expf(6.9077552789821368f * ((float)tid * (1.f / 72.f)));
            float t  = diff / dm;
            emb[tid]      = sinf(t);
            emb[72 + tid] = cosf(t);
        }
        __syncthreads();
        const float* W = axis ? Wy : Wx;
        unsigned short* F = axis ? FYb : FXb;
        for (int o = tid; o < CDIM; o += 256) {
            const float* wr = W + (size_t)o * 144;
            float s = 0.f;
#pragma unroll 9
            for (int f4 = 0; f4 < 36; ++f4) {
                float4 w4 = *(const float4*)&wr[f4 * 4];
                s += emb[f4 * 4 + 0] * w4.x + emb[f4 * 4 + 1] * w4.y
                   + emb[f4 * 4 + 2] * w4.z + emb[f4 * 4 + 3] * w4.w;
            }
            int m = o >> 5, d = o & 31;
            F[(size_t)(m * 8 + (dif >> 4)) * 512 + ((dif & 15) + 16 * (d >> 3)) * 8 + (d & 7)]
                = f2bf(s * 0.70710678118654752f);
        }
    } else if (b == 252) {
        for (int idx = tid; idx < 1152; idx += 256) {
            int d = idx & 31, rr = (idx >> 5) & 1, mm = (idx >> 6) % 9, ax = idx / 576;
            int dif = 126 + rr;
            unsigned short* F = ax ? FYb : FXb;
            F[(size_t)(mm * 8 + 7) * 512 + ((dif & 15) + 16 * (d >> 3)) * 8 + (d & 7)] = 0;
        }
        for (int p = tid; p < NB * CDIM; p += 256) {
            int n = p / CDIM, o = p % CDIM;
            const float* wr = Wq + (size_t)o * CDIM;
            const float* mx = MX + n * CDIM;
            float s = 0.f;
            for (int c = 0; c < CDIM; c += 4) {
                float4 w4 = *(const float4*)&wr[c];
                float4 m4 = *(const float4*)&mx[c];
                s += w4.x * m4.x + w4.y * m4.y + w4.z * m4.z + w4.w * m4.w;
            }
            ctx_s[p] = s;
        }
        __syncthreads();
        if (tid < 18) {
            int n = tid / 9, j = tid % 9;
            float s = bc[j];
            for (int o = 0; o < CDIM; ++o) s += ctx_s[n * CDIM + o] * Wc[j * CDIM + o];
            lg[tid] = s;
        }
        __syncthreads();
        if (tid < 2) {
            float mx = -1e30f;
            for (int j = 0; j < 9; ++j) mx = fmaxf(mx, lg[tid * 9 + j]);
            float e[9], sm = 0.f;
            for (int j = 0; j < 9; ++j) { e[j] = __expf(lg[tid * 9 + j] - mx); sm += e[j]; }
            for (int j = 0; j < 9; ++j) MIXW[tid * 9 + j] = e[j] / sm;
        }
    } else {
        int bx = b - 253;
        int gx = bx % 40;
        int m  = (bx / 40) % 9;
        int n  = bx / 360;
        int wv = tid >> 6, lane = tid & 63;
        int lq = lane & 15, quad = lane >> 4;
        if (gx < 32) {
            int j0 = gx * 128;
            int jw = j0 + wv * 32;
            const unsigned short* Wb = WFq + ((size_t)(m * 2) * 9) * 512 + lane * 8;
            const unsigned short* Xb = XF + (size_t)n * HW * CDIM + ((size_t)(jw >> 4) * 9) * 512 + lane * 8;
            f32x4 acc[2][2] = {};
#pragma unroll
            for (int cc = 0; cc < 9; ++cc) {
                bf16x8 a0 = *(const bf16x8*)(Wb + (size_t)cc * 512);
                bf16x8 a1 = *(const bf16x8*)(Wb + (size_t)(9 + cc) * 512);
                bf16x8 b0 = *(const bf16x8*)(Xb + (size_t)cc * 512);
                bf16x8 b1 = *(const bf16x8*)(Xb + (size_t)(9 + cc) * 512);
                acc[0][0] = __builtin_amdgcn_mfma_f32_16x16x32_bf16(a0, b0, acc[0][0], 0, 0, 0);
                acc[0][1] = __builtin_amdgcn_mfma_f32_16x16x32_bf16(a0, b1, acc[0][1], 0, 0, 0);
                acc[1][0] = __builtin_amdgcn_mfma_f32_16x16x32_bf16(a1, b0, acc[1][0], 0, 0, 0);
                acc[1][1] = __builtin_amdgcn_mfma_f32_16x16x32_bf16(a1, b1, acc[1][1], 0, 0, 0);
            }
#pragma unroll
            for (int oi = 0; oi < 2; ++oi)
#pragma unroll
                for (int ji = 0; ji < 2; ++ji)
#pragma unroll
                    for (int r = 0; r < 4; ++r)
                        tr[wv][ji * 16 + lq][oi * 16 + quad * 4 + r]
                            = f2bf(1.4426950408889634f * acc[oi][ji][r]);
            int jl = lane & 31, half = lane >> 5;
            bf16x8 v0 = *(const bf16x8*)&tr[wv][jl][half * 16];
            bf16x8 v1 = *(const bf16x8*)&tr[wv][jl][half * 16 + 8];
            unsigned short* Qm = Qf + ((size_t)(n * MHEAD + m) * HW + jw + jl) * 32 + half * 16;
            *(bf16x8*)Qm = v0;
            *(bf16x8*)(Qm + 8) = v1;
        } else {
            int p0 = (gx - 32) * 128;
            int pw = p0 + wv * 32;
            const unsigned short* XFn = XF + (size_t)n * HW * CDIM;
            size_t bidx[2];
#pragma unroll
            for (int pi = 0; pi < 2; ++pi) {
                int p   = pw + pi * 16 + lq;
                int pos = ((p >> 5) << 7) + ((p & 31) << 1);
                bidx[pi] = ((size_t)(pos >> 4) * 9) * 512 + ((pos & 15) + 16 * quad) * 8;
            }
            const unsigned short* Wkb = WFk + ((size_t)(m * 2) * 9) * 512 + lane * 8;
            const unsigned short* Wvb = WFv + ((size_t)(m * 2) * 9) * 512 + lane * 8;
            f32x4 ak[2][2] = {}, av[2][2] = {};
#pragma unroll
            for (int cc = 0; cc < 9; ++cc) {
                bf16x8 a0k = *(const bf16x8*)(Wkb + (size_t)cc * 512);
                bf16x8 a1k = *(const bf16x8*)(Wkb + (size_t)(9 + cc) * 512);
                bf16x8 a0v = *(const bf16x8*)(Wvb + (size_t)cc * 512);
                bf16x8 a1v = *(const bf16x8*)(Wvb + (size_t)(9 + cc) * 512);
                bf16x8 b0  = *(const bf16x8*)(XFn + bidx[0] + (size_t)cc * 512);
                bf16x8 b1  = *(const bf16x8*)(XFn + bidx[1] + (size_t)cc * 512);
                ak[0][0] = __builtin_amdgcn_mfma_f32_16x16x32_bf16(a0k, b0, ak[0][0], 0, 0, 0);
                ak[0][1] = __builtin_amdgcn_mfma_f32_16x16x32_bf16(a0k, b1, ak[0][1], 0, 0, 0);
                ak[1][0] = __builtin_amdgcn_mfma_f32_16x16x32_bf16(a1k, b0, ak[1][0], 0, 0, 0);
                ak[1][1] = __builtin_amdgcn_mfma_f32_16x16x32_bf16(a1k, b1, ak[1][1], 0, 0, 0);
                av[0][0] = __builtin_amdgcn_mfma_f32_16x16x32_bf16(a0v, b0, av[0][0], 0, 0, 0);
                av[0][1] = __builtin_amdgcn_mfma_f32_16x16x32_bf16(a0v, b1, av[0][1], 0, 0, 0);
                av[1][0] = __builtin_amdgcn_mfma_f32_16x16x32_bf16(a1v, b0, av[1][0], 0, 0, 0);
                av[1][1] = __builtin_amdgcn_mfma_f32_16x16x32_bf16(a1v, b1, av[1][1], 0, 0, 0);
            }
#pragma unroll
            for (int oi = 0; oi < 2; ++oi)
#pragma unroll
                for (int pi = 0; pi < 2; ++pi)
#pragma unroll
                    for (int r = 0; r < 4; ++r)
                        tr[wv][pi * 16 + lq][oi * 16 + quad * 4 + r] = f2bf(ak[oi][pi][r]);
            unsigned short* KFm = KF + (size_t)(n * MHEAD + m) * (PKV * 32);
#pragma unroll
            for (int pi = 0; pi < 2; ++pi) {
                bf16x8 v = *(const bf16x8*)&tr[wv][pi * 16 + lq][quad * 8];
                *(bf16x8*)(KFm + (size_t)((pw >> 4) + pi) * 512 + lane * 8) = v;
            }
#pragma unroll
            for (int oi = 0; oi < 2; ++oi)
#pragma unroll
                for (int pi = 0; pi < 2; ++pi)
#pragma unroll
                    for (int r = 0; r < 4; ++r)
                        tr[wv][oi * 16 + quad * 4 + r][pi * 16 + lq] = f2bf(av[oi][pi][r]);
            unsigned short* VFn = VF + (size_t)n * CDIM * PKV;
#pragma unroll
            for (int oi = 0; oi < 2; ++oi) {
                bf16x8 v = *(const bf16x8*)&tr[wv][oi * 16 + lq][quad * 8];
                *(bf16x8*)(VFn + (size_t)((m * 2 + oi) * 32 + (pw >> 5)) * 512 + lane * 8) = v;
            }
        }
    }
}

// ---------------------------------------------------------------------------
// attn_abl<V>: ablation family on the fused7 body (round-3 best, 61.9 us).
//  V=0 full (writes correct OUT; launched LAST)
//  V=1 no EXP2 (sum passes through)              -> trans-pipe cost
//  V=2 no softmax (fct=wm; no bias/exp/rs/shfl)  -> whole softmax block
//  V=3 all heads read head-0 K panel (L2-hot)    -> KF L2 miss/queue cost
//  V=4 no r_phase, ex=ey=0 (exp kept)            -> R-table produce+consume
//  V=5 no PV/proj (digest write after head loop) -> tail phases
//  All variants keep data flowing to a global write (no DCE).
template<int V>
__global__ __launch_bounds__(1024, 4) void attn_abl(
        const unsigned short* __restrict__ Qf, const unsigned short* __restrict__ KF,
        const unsigned short* __restrict__ VF, const unsigned short* __restrict__ WFp,
        const unsigned short* __restrict__ FXb, const unsigned short* __restrict__ FYb,
        const float* __restrict__ MIXW, const float* __restrict__ bproj,
        const float* __restrict__ x, const float* __restrict__ gamma,
        float* __restrict__ OUT) {
    int n    = blockIdx.x >> 7;
    int i0   = (blockIdx.x & 127) * 32;
    int tid  = threadIdx.x;
    int wv   = tid >> 6;
    int ti   = wv >> 3;
    int w8   = wv & 7;
    int lane = tid & 63;
    int lq   = lane & 15;
    int quad = lane >> 4;
    int it0  = i0 + ti * 16;

    int bx_t = (it0 & 63) >> 4;
    int hh   = i0 >> 6;
    int by_t = hh >> 4;
    int dh   = hh & 15;

    __shared__ __attribute__((aligned(16))) unsigned short tr[32][1032];
    float (*Rx_s)[2][16][82] = reinterpret_cast<float (*)[2][16][82]>((char*)&tr[0][0]);
    float (*Ry_s)[2][16][82] = reinterpret_cast<float (*)[2][16][82]>((char*)&tr[0][0] + 20992);
    float (*ws_s)[2][16][8]  = reinterpret_cast<float (*)[2][16][8]>((char*)&tr[0][0] + 41984);
    unsigned short (*Mt)[296] = reinterpret_cast<unsigned short (*)[296]>(&tr[0][0]);

    float mixed[8][4];
#pragma unroll
    for (int t = 0; t < 8; ++t)
#pragma unroll
        for (int j = 0; j < 4; ++j) mixed[t][j] = 0.f;

    auto r_phase = [&](int mm, bf16x8 af) {
        int pp = mm & 1;
        if (w8 < 5) {
            bf16x8 bR = *(const bf16x8*)(FXb + (size_t)(mm * 8 + bx_t + w8) * 512 + lane * 8);
            f32x4 r = (f32x4){0.f, 0.f, 0.f, 0.f};
            r = __builtin_amdgcn_mfma_f32_16x16x32_bf16(af, bR, r, 0, 0, 0);
#pragma unroll
            for (int reg = 0; reg < 4; ++reg)
                Rx_s[pp][ti][quad * 4 + reg][w8 * 16 + lq] = r[reg];
        } else {
            bf16x8 bR = *(const bf16x8*)(FYb + (size_t)(mm * 8 + by_t + (w8 - 5)) * 512 + lane * 8);
            f32x4 r = (f32x4){0.f, 0.f, 0.f, 0.f};
            r = __builtin_amdgcn_mfma_f32_16x16x32_bf16(af, bR, r, 0, 0, 0);
#pragma unroll
            for (int reg = 0; reg < 4; ++reg)
                Ry_s[pp][ti][quad * 4 + reg][(w8 - 5) * 16 + lq] = r[reg];
        }
        if (w8 < 2) {
            bf16x8 bR = *(const bf16x8*)(FYb + (size_t)(mm * 8 + by_t + 3 + w8) * 512 + lane * 8);
            f32x4 r = (f32x4){0.f, 0.f, 0.f, 0.f};
            r = __builtin_amdgcn_mfma_f32_16x16x32_bf16(af, bR, r, 0, 0, 0);
#pragma unroll
            for (int reg = 0; reg < 4; ++reg)
                Ry_s[pp][ti][quad * 4 + reg][(3 + w8) * 16 + lq] = r[reg];
        }
    };

    bf16x8 af_cur = *(const bf16x8*)(Qf + (((size_t)n * MHEAD) * HW + it0 + lq) * 32 + quad * 8);
    if constexpr (V != 4) r_phase(0, af_cur);
    __syncthreads();

#pragma unroll 1
    for (int m = 0; m < MHEAD; ++m) {
        int mk = (V == 3) ? 0 : m;     // V3: L2-hot K panel
        const unsigned short* KmF = KF + (size_t)(n * MHEAD + mk) * (PKV * 32);
        bf16x8 kf[8];
#pragma unroll
        for (int t = 0; t < 8; ++t)
            kf[t] = *(const bf16x8*)(KmF + (size_t)(w8 * 8 + t) * 512 + lane * 8);

        bf16x8 af_nxt = af_cur;
        __builtin_amdgcn_s_setprio(1);
        if (m + 1 < MHEAD) {
            af_nxt = *(const bf16x8*)(Qf + (((size_t)(n * MHEAD + m + 1)) * HW + it0 + lq) * 32 + quad * 8);
            if constexpr (V != 4) r_phase(m + 1, af_nxt);
        }
        f32x4 acc[8];
#pragma unroll
        for (int t = 0; t < 8; ++t) {
            f32x4 z = (f32x4){0.f, 0.f, 0.f, 0.f};
            acc[t] = __builtin_amdgcn_mfma_f32_16x16x32_bf16(af_cur, kf[t], z, 0, 0, 0);
        }
        __builtin_amdgcn_s_setprio(0);

        int par = m & 1;
        if constexpr (V != 2) {
            float exA[4], exB[4];
#pragma unroll
            for (int j = 0; j < 4; ++j) {
                if constexpr (V == 4) { exA[j] = 0.f; exB[j] = 0.f; }
                else {
                    int q = quad * 4 + j;
                    exA[j] = Rx_s[par][ti][q][q + 62 - 2 * lq];
                    exB[j] = Rx_s[par][ti][q][q + 30 - 2 * lq];
                }
            }
            float rs[4] = {0.f, 0.f, 0.f, 0.f};
#pragma unroll
            for (int tp = 0; tp < 4; ++tp) {
                int u = w8 * 4 + tp;
                float ey[4];
#pragma unroll
                for (int j = 0; j < 4; ++j)
                    ey[j] = (V == 4) ? 0.f : Ry_s[par][ti][quad * 4 + j][dh + 62 - 2 * u];
#pragma unroll
                for (int half = 0; half < 2; ++half) {
                    int t = tp * 2 + half;
#pragma unroll
                    for (int j = 0; j < 4; ++j) {
                        float s = acc[t][j] + (half ? exB[j] : exA[j]) + ey[j];
                        float e = (V == 1) ? s : EXP2(s);
                        rs[j] += e;
                        acc[t][j] = e;
                    }
                }
            }
#pragma unroll
            for (int j = 0; j < 4; ++j) {
                rs[j] += __shfl_xor(rs[j], 1, 64);
                rs[j] += __shfl_xor(rs[j], 2, 64);
                rs[j] += __shfl_xor(rs[j], 4, 64);
                rs[j] += __shfl_xor(rs[j], 8, 64);
            }
            if (lq == 0) {
#pragma unroll
                for (int j = 0; j < 4; ++j) ws_s[par][ti][quad * 4 + j][w8] = rs[j];
            }
        }
        __syncthreads();

        {
            float wm = MIXW[n * MHEAD + m];
#pragma unroll
            for (int j = 0; j < 4; ++j) {
                float fct;
                if constexpr (V == 2) {
                    fct = wm;
                } else {
                    int q = quad * 4 + j;
                    float4 w0 = *(const float4*)&ws_s[par][ti][q][0];
                    float4 w1 = *(const float4*)&ws_s[par][ti][q][4];
                    float lt = (w0.x + w0.y) + (w0.z + w0.w) + (w1.x + w1.y) + (w1.z + w1.w);
                    fct = wm / lt;
                }
#pragma unroll
                for (int t = 0; t < 8; ++t) mixed[t][j] += acc[t][j] * fct;
            }
        }
        __builtin_amdgcn_sched_barrier(0);
        af_cur = af_nxt;
    }

    if constexpr (V == 5) {
        // digest write keeps the whole head loop live; overwritten by V0 later
        float dg = 0.f;
#pragma unroll
        for (int t = 0; t < 8; ++t)
#pragma unroll
            for (int j = 0; j < 4; ++j) dg += mixed[t][j];
        OUT[(size_t)blockIdx.x * 1024 + tid] = dg;
        return;
    }

    __syncthreads();

#pragma unroll
    for (int t = 0; t < 8; ++t)
#pragma unroll
        for (int j = 0; j < 4; ++j)
            tr[ti * 16 + quad * 4 + j][w8 * 128 + t * 16 + lq] = f2bf(mixed[t][j]);
    __syncthreads();

    const unsigned short* VFn = VF + (size_t)n * CDIM * PKV;
    f32x4 accpv[2][2];
#pragma unroll
    for (int oi = 0; oi < 2; ++oi)
#pragma unroll
        for (int t2 = 0; t2 < 2; ++t2) accpv[oi][t2] = (f32x4){0.f, 0.f, 0.f, 0.f};
    bool has2 = (wv < 2);
#pragma unroll 4
    for (int pc = 0; pc < 32; ++pc) {
        bf16x8 pf0 = *(const bf16x8*)&tr[lq][pc * 32 + quad * 8];
        bf16x8 pf1 = *(const bf16x8*)&tr[16 + lq][pc * 32 + quad * 8];
        bf16x8 vf0 = *(const bf16x8*)(VFn + (size_t)(wv * 32 + pc) * 512 + lane * 8);
        accpv[0][0] = __builtin_amdgcn_mfma_f32_16x16x32_bf16(pf0, vf0, accpv[0][0], 0, 0, 0);
        accpv[0][1] = __builtin_amdgcn_mfma_f32_16x16x32_bf16(pf1, vf0, accpv[0][1], 0, 0, 0);
        if (has2) {
            bf16x8 vf1 = *(const bf16x8*)(VFn + (size_t)((wv + 16) * 32 + pc) * 512 + lane * 8);
            accpv[1][0] = __builtin_amdgcn_mfma_f32_16x16x32_bf16(pf0, vf1, accpv[1][0], 0, 0, 0);
            accpv[1][1] = __builtin_amdgcn_mfma_f32_16x16x32_bf16(pf1, vf1, accpv[1][1], 0, 0, 0);
        }
    }
    __syncthreads();

#pragma unroll
    for (int oi = 0; oi < 2; ++oi) {
        if (oi == 1 && !has2) continue;
        int ot = wv + oi * 16;
#pragma unroll
        for (int t2 = 0; t2 < 2; ++t2)
#pragma unroll
            for (int r = 0; r < 4; ++r)
                Mt[t2 * 16 + quad * 4 + r][ot * 16 + lq] = f2bf(accpv[oi][t2][r]);
    }
    __syncthreads();

    float g = gamma[0];
#pragma unroll
    for (int idx = 0; idx < 3; ++idx) {
        int ot = w8 + idx * 8;
        if (ot >= 18) continue;
        f32x4 acco = (f32x4){0.f, 0.f, 0.f, 0.f};
#pragma unroll
        for (int cc = 0; cc < 9; ++cc) {
            bf16x8 af = *(const bf16x8*)(WFp + (size_t)(ot * 9 + cc) * 512 + lane * 8);
            bf16x8 bfm = *(const bf16x8*)&Mt[ti * 16 + lq][cc * 32 + quad * 8];
            acco = __builtin_amdgcn_mfma_f32_16x16x32_bf16(af, bfm, acco, 0, 0, 0);
        }
#pragma unroll
        for (int r = 0; r < 4; ++r) {
            int o = ot * 16 + quad * 4 + r;
            size_t id = ((size_t)(n * CDIM) + o) * HW + it0 + lq;
            OUT[id] = g * (acco[r] + bproj[o]) + x[id];
        }
    }
}

// ---------------------------------------------------------------------------
extern "C" void kernel_launch(void* const* d_in, const int* in_sizes, int n_in,
                              void* d_out, int out_size, void* d_ws, size_t ws_size,
                              hipStream_t stream) {
    const float* x     = (const float*)d_in[0];
    const float* Wq    = (const float*)d_in[1];
    const float* Wk    = (const float*)d_in[2];
    const float* Wv    = (const float*)d_in[3];
    const float* Wx    = (const float*)d_in[4];
    const float* Wy    = (const float*)d_in[5];
    const float* Wproj = (const float*)d_in[6];
    const float* bproj = (const float*)d_in[7];
    const float* Wc    = (const float*)d_in[8];
    const float* bc    = (const float*)d_in[9];
    const float* gamma = (const float*)d_in[10];
    float* out = (float*)d_out;

    float* ws = (float*)d_ws;
    size_t off = 0;
    unsigned short* Qf  = (unsigned short*)(ws + off); off += (size_t)NB * MHEAD * HW * 32 / 2;
    unsigned short* KF  = (unsigned short*)(ws + off); off += (size_t)NB * MHEAD * PKV * 32 / 2;
    unsigned short* VF  = (unsigned short*)(ws + off); off += (size_t)NB * CDIM * PKV / 2;
    unsigned short* WFq = (unsigned short*)(ws + off); off += (size_t)CDIM * CDIM / 2;
    unsigned short* WFk = (unsigned short*)(ws + off); off += (size_t)CDIM * CDIM / 2;
    unsigned short* WFv = (unsigned short*)(ws + off); off += (size_t)CDIM * CDIM / 2;
    unsigned short* WFp = (unsigned short*)(ws + off); off += (size_t)CDIM * CDIM / 2;
    unsigned short* XF  = (unsigned short*)(ws + off); off += (size_t)NB * HW * CDIM / 2;
    unsigned short* FXb = (unsigned short*)(ws + off); off += (size_t)MHEAD * 8 * 512 / 2;
    unsigned short* FYb = (unsigned short*)(ws + off); off += (size_t)MHEAD * 8 * 512 / 2;
    float* MX   = ws + off; off += NB * CDIM;
    float* MIXW = ws + off; off += 32;

    prep<<<1314, 256, 0, stream>>>(x, Wq, Wk, Wv, Wproj,
                                   XF, WFq, WFk, WFv, WFp, MX);
    mid<<<973, 256, 0, stream>>>(Wx, Wy, FXb, FYb, Wq, MX, Wc, bc, MIXW,
                                 WFq, WFk, WFv, XF, Qf, KF, VF);
    // ---- ablation dispatches (outputs overwritten by the final V0 pass)
    attn_abl<1><<<NB * HW / 32, 1024, 0, stream>>>(Qf, KF, VF, WFp, FXb, FYb, MIXW, bproj, x, gamma, out);
    attn_abl<2><<<NB * HW / 32, 1024, 0, stream>>>(Qf, KF, VF, WFp, FXb, FYb, MIXW, bproj, x, gamma, out);
    attn_abl<3><<<NB * HW / 32, 1024, 0, stream>>>(Qf, KF, VF, WFp, FXb, FYb, MIXW, bproj, x, gamma, out);
    attn_abl<4><<<NB * HW / 32, 1024, 0, stream>>>(Qf, KF, VF, WFp, FXb, FYb, MIXW, bproj, x, gamma, out);
    attn_abl<5><<<NB * HW / 32, 1024, 0, stream>>>(Qf, KF, VF, WFp, FXb, FYb, MIXW, bproj, x, gamma, out);
    // ---- real pass (correct OUT)
    attn_abl<0><<<NB * HW / 32, 1024, 0, stream>>>(Qf, KF, VF, WFp, FXb, FYb, MIXW, bproj, x, gamma, out);
}

// Round 9
// 186.112 us; speedup vs baseline: 2.1980x; 2.1980x over previous
//
#include <hip/hip_runtime.h>
#include <math.h>

// n=2, C=288, h=w=64 -> hw=4096; kv stride 2 -> 32x32 -> pkv=1024; M=9 heads, d=32
#define NB     2
#define CDIM   288
#define HW     4096
#define PKV    1024
#define MHEAD  9
#define DHEAD  32

typedef __attribute__((ext_vector_type(8))) short bf16x8;
typedef __attribute__((ext_vector_type(4))) float f32x4;
typedef __attribute__((ext_vector_type(2))) unsigned int u32x2;
typedef __attribute__((ext_vector_type(4))) unsigned int u32x4;

#if __has_builtin(__builtin_amdgcn_exp2f)
#define EXP2(x) __builtin_amdgcn_exp2f(x)
#else
#define EXP2(x) exp2f(x)
#endif

__device__ inline unsigned short f2bf(float x) {
    unsigned int u = __float_as_uint(x);
    u = (u + 0x7fffu + ((u >> 16) & 1u)) >> 16;
    return (unsigned short)u;
}

// non-temporal stores: producer->consumer data crosses kernels; nt keeps the
// lines out of the producer's per-XCD L2 (clean in HBM/L3), so the consumer's
// first-touch reads avoid the cross-XCD dirty-snoop path (round-6 finding:
// first attn pass pays ~15-20us absorbing mid's writebacks).
// NOTE round-7: __builtin_nontemporal_store requires clang ext_vector types,
// not HIP_vector_type classes (uint2/uint4) -- use u32x2/u32x4.
__device__ inline void nt_store_u2(unsigned short* p, u32x2 v) {
    __builtin_nontemporal_store(v, (u32x2*)p);
}
__device__ inline void nt_store_u4(unsigned short* p, u32x4 v) {
    __builtin_nontemporal_store(v, (u32x4*)p);
}
__device__ inline void nt_store_bf8(unsigned short* p, bf16x8 v) {
    __builtin_nontemporal_store(v, (bf16x8*)p);
}

// ---------------------------------------------------------------------------
// Fragment-major tile (16 rows r, 32 k): elem(r,k) = ((r&15)+16*(k>>3))*8 + (k&7)
//  WF (A-side, rows=o, k=c): tiles (ot,cc) -> (ot*9+cc)*512
//  XF (B-side, rows=j, k=c): per n, (jt,cc) -> (jt*9+cc)*512
//  KF (B-side, rows=p, k=d): per (n,m), pt -> pt*512
//  VF (B-side, rows=o, k=p): per n, (ot,pc) -> (ot*32+pc)*512
//  FXb/FYb (B-side, rows=dif[128 padded], k=d): per m, tile t -> (m*8+t)*512

// ---------------------------------------------------------------------------
// prep: fused xtransF (float4) + wcvtF + meanx.
__global__ __launch_bounds__(256) void prep(const float* __restrict__ X,
        const float* __restrict__ Wq, const float* __restrict__ Wk,
        const float* __restrict__ Wv, const float* __restrict__ Wproj,
        unsigned short* __restrict__ XF, unsigned short* __restrict__ WFq,
        unsigned short* __restrict__ WFk, unsigned short* __restrict__ WFv,
        unsigned short* __restrict__ WFp, float* __restrict__ MX) {
    __shared__ float t32[32][133];
    __shared__ float red[4];
    int b = blockIdx.x;
    int tid = threadIdx.x;
    if (b < 576) {
        int bx = b % 32, by = (b / 32) % 9, n = b / 288;
        int j0 = bx * 128, c0 = by * 32;
        int c = tid >> 3, f = tid & 7;
        const float* src = &X[((size_t)n * CDIM + c0 + c) * HW + j0];
#pragma unroll
        for (int l = 0; l < 4; ++l) {
            float4 v = *(const float4*)&src[(f + l * 8) * 4];
            *(float4*)&t32[c][(f + l * 8) * 4] = v;
        }
        __syncthreads();
        int cc = c0 >> 5;
#pragma unroll
        for (int l = 0; l < 4; ++l) {
            int g = l * 256 + tid;
            int s = g >> 7;
            int w = g & 127;
            int lane = w >> 1, e0 = (w & 1) * 4;
            int jl = s * 16 + (lane & 15);
            int cb = (lane >> 4) * 8 + e0;
            unsigned int w0 = f2bf(t32[cb + 0][jl]) | ((unsigned int)f2bf(t32[cb + 1][jl]) << 16);
            unsigned int w1 = f2bf(t32[cb + 2][jl]) | ((unsigned int)f2bf(t32[cb + 3][jl]) << 16);
            int jt = (j0 >> 4) + s;
            unsigned short* O = XF + (size_t)n * HW * CDIM + ((size_t)jt * 9 + cc) * 512 + lane * 8 + e0;
            u32x2 pk = { w0, w1 };
            nt_store_u2(O, pk);
        }
    } else if (b < 738) {
        int t = b - 576;
        int sub = tid >> 6, lane = tid & 63;
        int ot = t / 9, cc = t % 9;
        const float* W = (sub == 0) ? Wq : (sub == 1) ? Wk : (sub == 2) ? Wv : Wproj;
        unsigned short* O = ((sub == 0) ? WFq : (sub == 1) ? WFk : (sub == 2) ? WFv : WFp)
                            + (size_t)t * 512;
        int o  = ot * 16 + (lane & 15);
        int c0 = cc * 32 + (lane >> 4) * 8;
        const float* src = W + (size_t)o * CDIM + c0;
        float4 f0 = *(const float4*)src, f1 = *(const float4*)(src + 4);
        unsigned int v0 = f2bf(f0.x) | ((unsigned int)f2bf(f0.y) << 16);
        unsigned int v1 = f2bf(f0.z) | ((unsigned int)f2bf(f0.w) << 16);
        unsigned int v2 = f2bf(f1.x) | ((unsigned int)f2bf(f1.y) << 16);
        unsigned int v3 = f2bf(f1.z) | ((unsigned int)f2bf(f1.w) << 16);
        u32x4 pk = { v0, v1, v2, v3 };
        nt_store_u4(O + lane * 8, pk);
    } else {
        int bid = b - 738;
        const float* xr = X + (size_t)bid * HW;
        float s = 0.f;
        for (int j = tid; j < HW; j += 256) s += xr[j];
        for (int off = 32; off > 0; off >>= 1) s += __shfl_xor(s, off, 64);
        if ((tid & 63) == 0) red[tid >> 6] = s;
        __syncthreads();
        if (tid == 0) MX[bid] = (red[0] + red[1] + red[2] + red[3]) * (1.f / 4096.f);
    }
}

// ---------------------------------------------------------------------------
// mid: fused pff + mixw2 + qkv.  Qf pre-scaled by log2(e); nt stores on all
// attn-consumed outputs.
__global__ __launch_bounds__(256) void mid(
        const float* __restrict__ Wx, const float* __restrict__ Wy,
        unsigned short* __restrict__ FXb, unsigned short* __restrict__ FYb,
        const float* __restrict__ Wq, const float* __restrict__ MX,
        const float* __restrict__ Wc, const float* __restrict__ bc,
        float* __restrict__ MIXW,
        const unsigned short* __restrict__ WFq, const unsigned short* __restrict__ WFk,
        const unsigned short* __restrict__ WFv, const unsigned short* __restrict__ XF,
        unsigned short* __restrict__ Qf, unsigned short* __restrict__ KF,
        unsigned short* __restrict__ VF) {
    __shared__ float emb[144];
    __shared__ float ctx_s[NB * CDIM];
    __shared__ float lg[18];
    __shared__ __attribute__((aligned(16))) unsigned short tr[4][32][40];
    int b = blockIdx.x;
    int tid = threadIdx.x;

    if (b < 252) {
        int axis = b / 126;
        int dif  = b % 126;
        float diff = (float)(dif - 62);
        if (tid < 72) {
            float dm = expf(6.9077552789821368f * ((float)tid * (1.f / 72.f)));
            float t  = diff / dm;
            emb[tid]      = sinf(t);
            emb[72 + tid] = cosf(t);
        }
        __syncthreads();
        const float* W = axis ? Wy : Wx;
        unsigned short* F = axis ? FYb : FXb;
        for (int o = tid; o < CDIM; o += 256) {
            const float* wr = W + (size_t)o * 144;
            float s = 0.f;
#pragma unroll 9
            for (int f4 = 0; f4 < 36; ++f4) {
                float4 w4 = *(const float4*)&wr[f4 * 4];
                s += emb[f4 * 4 + 0] * w4.x + emb[f4 * 4 + 1] * w4.y
                   + emb[f4 * 4 + 2] * w4.z + emb[f4 * 4 + 3] * w4.w;
            }
            int m = o >> 5, d = o & 31;
            F[(size_t)(m * 8 + (dif >> 4)) * 512 + ((dif & 15) + 16 * (d >> 3)) * 8 + (d & 7)]
                = f2bf(s * 0.70710678118654752f);
        }
    } else if (b == 252) {
        for (int idx = tid; idx < 1152; idx += 256) {
            int d = idx & 31, rr = (idx >> 5) & 1, mm = (idx >> 6) % 9, ax = idx / 576;
            int dif = 126 + rr;
            unsigned short* F = ax ? FYb : FXb;
            F[(size_t)(mm * 8 + 7) * 512 + ((dif & 15) + 16 * (d >> 3)) * 8 + (d & 7)] = 0;
        }
        for (int p = tid; p < NB * CDIM; p += 256) {
            int n = p / CDIM, o = p % CDIM;
            const float* wr = Wq + (size_t)o * CDIM;
            const float* mx = MX + n * CDIM;
            float s = 0.f;
            for (int c = 0; c < CDIM; c += 4) {
                float4 w4 = *(const float4*)&wr[c];
                float4 m4 = *(const float4*)&mx[c];
                s += w4.x * m4.x + w4.y * m4.y + w4.z * m4.z + w4.w * m4.w;
            }
            ctx_s[p] = s;
        }
        __syncthreads();
        if (tid < 18) {
            int n = tid / 9, j = tid % 9;
            float s = bc[j];
            for (int o = 0; o < CDIM; ++o) s += ctx_s[n * CDIM + o] * Wc[j * CDIM + o];
            lg[tid] = s;
        }
        __syncthreads();
        if (tid < 2) {
            float mx = -1e30f;
            for (int j = 0; j < 9; ++j) mx = fmaxf(mx, lg[tid * 9 + j]);
            float e[9], sm = 0.f;
            for (int j = 0; j < 9; ++j) { e[j] = __expf(lg[tid * 9 + j] - mx); sm += e[j]; }
            for (int j = 0; j < 9; ++j) MIXW[tid * 9 + j] = e[j] / sm;
        }
    } else {
        int bx = b - 253;
        int gx = bx % 40;
        int m  = (bx / 40) % 9;
        int n  = bx / 360;
        int wv = tid >> 6, lane = tid & 63;
        int lq = lane & 15, quad = lane >> 4;
        if (gx < 32) {
            int j0 = gx * 128;
            int jw = j0 + wv * 32;
            const unsigned short* Wb = WFq + ((size_t)(m * 2) * 9) * 512 + lane * 8;
            const unsigned short* Xb = XF + (size_t)n * HW * CDIM + ((size_t)(jw >> 4) * 9) * 512 + lane * 8;
            f32x4 acc[2][2] = {};
#pragma unroll
            for (int cc = 0; cc < 9; ++cc) {
                bf16x8 a0 = *(const bf16x8*)(Wb + (size_t)cc * 512);
                bf16x8 a1 = *(const bf16x8*)(Wb + (size_t)(9 + cc) * 512);
                bf16x8 b0 = *(const bf16x8*)(Xb + (size_t)cc * 512);
                bf16x8 b1 = *(const bf16x8*)(Xb + (size_t)(9 + cc) * 512);
                acc[0][0] = __builtin_amdgcn_mfma_f32_16x16x32_bf16(a0, b0, acc[0][0], 0, 0, 0);
                acc[0][1] = __builtin_amdgcn_mfma_f32_16x16x32_bf16(a0, b1, acc[0][1], 0, 0, 0);
                acc[1][0] = __builtin_amdgcn_mfma_f32_16x16x32_bf16(a1, b0, acc[1][0], 0, 0, 0);
                acc[1][1] = __builtin_amdgcn_mfma_f32_16x16x32_bf16(a1, b1, acc[1][1], 0, 0, 0);
            }
#pragma unroll
            for (int oi = 0; oi < 2; ++oi)
#pragma unroll
                for (int ji = 0; ji < 2; ++ji)
#pragma unroll
                    for (int r = 0; r < 4; ++r)
                        tr[wv][ji * 16 + lq][oi * 16 + quad * 4 + r]
                            = f2bf(1.4426950408889634f * acc[oi][ji][r]);
            int jl = lane & 31, half = lane >> 5;
            bf16x8 v0 = *(const bf16x8*)&tr[wv][jl][half * 16];
            bf16x8 v1 = *(const bf16x8*)&tr[wv][jl][half * 16 + 8];
            unsigned short* Qm = Qf + ((size_t)(n * MHEAD + m) * HW + jw + jl) * 32 + half * 16;
            nt_store_bf8(Qm, v0);
            nt_store_bf8(Qm + 8, v1);
        } else {
            int p0 = (gx - 32) * 128;
            int pw = p0 + wv * 32;
            const unsigned short* XFn = XF + (size_t)n * HW * CDIM;
            size_t bidx[2];
#pragma unroll
            for (int pi = 0; pi < 2; ++pi) {
                int p   = pw + pi * 16 + lq;
                int pos = ((p >> 5) << 7) + ((p & 31) << 1);
                bidx[pi] = ((size_t)(pos >> 4) * 9) * 512 + ((pos & 15) + 16 * quad) * 8;
            }
            const unsigned short* Wkb = WFk + ((size_t)(m * 2) * 9) * 512 + lane * 8;
            const unsigned short* Wvb = WFv + ((size_t)(m * 2) * 9) * 512 + lane * 8;
            f32x4 ak[2][2] = {}, av[2][2] = {};
#pragma unroll
            for (int cc = 0; cc < 9; ++cc) {
                bf16x8 a0k = *(const bf16x8*)(Wkb + (size_t)cc * 512);
                bf16x8 a1k = *(const bf16x8*)(Wkb + (size_t)(9 + cc) * 512);
                bf16x8 a0v = *(const bf16x8*)(Wvb + (size_t)cc * 512);
                bf16x8 a1v = *(const bf16x8*)(Wvb + (size_t)(9 + cc) * 512);
                bf16x8 b0  = *(const bf16x8*)(XFn + bidx[0] + (size_t)cc * 512);
                bf16x8 b1  = *(const bf16x8*)(XFn + bidx[1] + (size_t)cc * 512);
                ak[0][0] = __builtin_amdgcn_mfma_f32_16x16x32_bf16(a0k, b0, ak[0][0], 0, 0, 0);
                ak[0][1] = __builtin_amdgcn_mfma_f32_16x16x32_bf16(a0k, b1, ak[0][1], 0, 0, 0);
                ak[1][0] = __builtin_amdgcn_mfma_f32_16x16x32_bf16(a1k, b0, ak[1][0], 0, 0, 0);
                ak[1][1] = __builtin_amdgcn_mfma_f32_16x16x32_bf16(a1k, b1, ak[1][1], 0, 0, 0);
                av[0][0] = __builtin_amdgcn_mfma_f32_16x16x32_bf16(a0v, b0, av[0][0], 0, 0, 0);
                av[0][1] = __builtin_amdgcn_mfma_f32_16x16x32_bf16(a0v, b1, av[0][1], 0, 0, 0);
                av[1][0] = __builtin_amdgcn_mfma_f32_16x16x32_bf16(a1v, b0, av[1][0], 0, 0, 0);
                av[1][1] = __builtin_amdgcn_mfma_f32_16x16x32_bf16(a1v, b1, av[1][1], 0, 0, 0);
            }
#pragma unroll
            for (int oi = 0; oi < 2; ++oi)
#pragma unroll
                for (int pi = 0; pi < 2; ++pi)
#pragma unroll
                    for (int r = 0; r < 4; ++r)
                        tr[wv][pi * 16 + lq][oi * 16 + quad * 4 + r] = f2bf(ak[oi][pi][r]);
            unsigned short* KFm = KF + (size_t)(n * MHEAD + m) * (PKV * 32);
#pragma unroll
            for (int pi = 0; pi < 2; ++pi) {
                bf16x8 v = *(const bf16x8*)&tr[wv][pi * 16 + lq][quad * 8];
                nt_store_bf8(KFm + (size_t)((pw >> 4) + pi) * 512 + lane * 8, v);
            }
#pragma unroll
            for (int oi = 0; oi < 2; ++oi)
#pragma unroll
                for (int pi = 0; pi < 2; ++pi)
#pragma unroll
                    for (int r = 0; r < 4; ++r)
                        tr[wv][oi * 16 + quad * 4 + r][pi * 16 + lq] = f2bf(av[oi][pi][r]);
            unsigned short* VFn = VF + (size_t)n * CDIM * PKV;
#pragma unroll
            for (int oi = 0; oi < 2; ++oi) {
                bf16x8 v = *(const bf16x8*)&tr[wv][oi * 16 + lq][quad * 8];
                nt_store_bf8(VFn + (size_t)((m * 2 + oi) * 32 + (pw >> 5)) * 512 + lane * 8, v);
            }
        }
    }
}

// ---------------------------------------------------------------------------
// attn_fused9: fused7 body (round-3/6 verified best), single instantiation.
__global__ __launch_bounds__(1024, 4) void attn_fused9(
        const unsigned short* __restrict__ Qf, const unsigned short* __restrict__ KF,
        const unsigned short* __restrict__ VF, const unsigned short* __restrict__ WFp,
        const unsigned short* __restrict__ FXb, const unsigned short* __restrict__ FYb,
        const float* __restrict__ MIXW, const float* __restrict__ bproj,
        const float* __restrict__ x, const float* __restrict__ gamma,
        float* __restrict__ OUT) {
    int n    = blockIdx.x >> 7;
    int i0   = (blockIdx.x & 127) * 32;
    int tid  = threadIdx.x;
    int wv   = tid >> 6;
    int ti   = wv >> 3;
    int w8   = wv & 7;
    int lane = tid & 63;
    int lq   = lane & 15;
    int quad = lane >> 4;
    int it0  = i0 + ti * 16;

    int bx_t = (it0 & 63) >> 4;
    int hh   = i0 >> 6;
    int by_t = hh >> 4;
    int dh   = hh & 15;

    __shared__ __attribute__((aligned(16))) unsigned short tr[32][1032];
    float (*Rx_s)[2][16][82] = reinterpret_cast<float (*)[2][16][82]>((char*)&tr[0][0]);
    float (*Ry_s)[2][16][82] = reinterpret_cast<float (*)[2][16][82]>((char*)&tr[0][0] + 20992);
    float (*ws_s)[2][16][8]  = reinterpret_cast<float (*)[2][16][8]>((char*)&tr[0][0] + 41984);
    unsigned short (*Mt)[296] = reinterpret_cast<unsigned short (*)[296]>(&tr[0][0]);

    float mixed[8][4];
#pragma unroll
    for (int t = 0; t < 8; ++t)
#pragma unroll
        for (int j = 0; j < 4; ++j) mixed[t][j] = 0.f;

    auto r_phase = [&](int mm, bf16x8 af) {
        int pp = mm & 1;
        if (w8 < 5) {
            bf16x8 bR = *(const bf16x8*)(FXb + (size_t)(mm * 8 + bx_t + w8) * 512 + lane * 8);
            f32x4 r = (f32x4){0.f, 0.f, 0.f, 0.f};
            r = __builtin_amdgcn_mfma_f32_16x16x32_bf16(af, bR, r, 0, 0, 0);
#pragma unroll
            for (int reg = 0; reg < 4; ++reg)
                Rx_s[pp][ti][quad * 4 + reg][w8 * 16 + lq] = r[reg];
        } else {
            bf16x8 bR = *(const bf16x8*)(FYb + (size_t)(mm * 8 + by_t + (w8 - 5)) * 512 + lane * 8);
            f32x4 r = (f32x4){0.f, 0.f, 0.f, 0.f};
            r = __builtin_amdgcn_mfma_f32_16x16x32_bf16(af, bR, r, 0, 0, 0);
#pragma unroll
            for (int reg = 0; reg < 4; ++reg)
                Ry_s[pp][ti][quad * 4 + reg][(w8 - 5) * 16 + lq] = r[reg];
        }
        if (w8 < 2) {
            bf16x8 bR = *(const bf16x8*)(FYb + (size_t)(mm * 8 + by_t + 3 + w8) * 512 + lane * 8);
            f32x4 r = (f32x4){0.f, 0.f, 0.f, 0.f};
            r = __builtin_amdgcn_mfma_f32_16x16x32_bf16(af, bR, r, 0, 0, 0);
#pragma unroll
            for (int reg = 0; reg < 4; ++reg)
                Ry_s[pp][ti][quad * 4 + reg][(3 + w8) * 16 + lq] = r[reg];
        }
    };

    bf16x8 af_cur = *(const bf16x8*)(Qf + (((size_t)n * MHEAD) * HW + it0 + lq) * 32 + quad * 8);
    r_phase(0, af_cur);
    __syncthreads();

#pragma unroll 1
    for (int m = 0; m < MHEAD; ++m) {
        const unsigned short* KmF = KF + (size_t)(n * MHEAD + m) * (PKV * 32);
        bf16x8 kf[8];
#pragma unroll
        for (int t = 0; t < 8; ++t)
            kf[t] = *(const bf16x8*)(KmF + (size_t)(w8 * 8 + t) * 512 + lane * 8);

        bf16x8 af_nxt = af_cur;
        __builtin_amdgcn_s_setprio(1);
        if (m + 1 < MHEAD) {
            af_nxt = *(const bf16x8*)(Qf + (((size_t)(n * MHEAD + m + 1)) * HW + it0 + lq) * 32 + quad * 8);
            r_phase(m + 1, af_nxt);
        }
        f32x4 acc[8];
#pragma unroll
        for (int t = 0; t < 8; ++t) {
            f32x4 z = (f32x4){0.f, 0.f, 0.f, 0.f};
            acc[t] = __builtin_amdgcn_mfma_f32_16x16x32_bf16(af_cur, kf[t], z, 0, 0, 0);
        }
        __builtin_amdgcn_s_setprio(0);

        int par = m & 1;
        float exA[4], exB[4];
#pragma unroll
        for (int j = 0; j < 4; ++j) {
            int q = quad * 4 + j;
            exA[j] = Rx_s[par][ti][q][q + 62 - 2 * lq];
            exB[j] = Rx_s[par][ti][q][q + 30 - 2 * lq];
        }
        float rs[4] = {0.f, 0.f, 0.f, 0.f};
#pragma unroll
        for (int tp = 0; tp < 4; ++tp) {
            int u = w8 * 4 + tp;
            float ey[4];
#pragma unroll
            for (int j = 0; j < 4; ++j) ey[j] = Ry_s[par][ti][quad * 4 + j][dh + 62 - 2 * u];
#pragma unroll
            for (int half = 0; half < 2; ++half) {
                int t = tp * 2 + half;
#pragma unroll
                for (int j = 0; j < 4; ++j) {
                    float e = EXP2(acc[t][j] + (half ? exB[j] : exA[j]) + ey[j]);
                    rs[j] += e;
                    acc[t][j] = e;
                }
            }
        }
#pragma unroll
        for (int j = 0; j < 4; ++j) {
            rs[j] += __shfl_xor(rs[j], 1, 64);
            rs[j] += __shfl_xor(rs[j], 2, 64);
            rs[j] += __shfl_xor(rs[j], 4, 64);
            rs[j] += __shfl_xor(rs[j], 8, 64);
        }
        if (lq == 0) {
#pragma unroll
            for (int j = 0; j < 4; ++j) ws_s[par][ti][quad * 4 + j][w8] = rs[j];
        }
        __syncthreads();

        {
            float wm = MIXW[n * MHEAD + m];
#pragma unroll
            for (int j = 0; j < 4; ++j) {
                int q = quad * 4 + j;
                float4 w0 = *(const float4*)&ws_s[par][ti][q][0];
                float4 w1 = *(const float4*)&ws_s[par][ti][q][4];
                float lt = (w0.x + w0.y) + (w0.z + w0.w) + (w1.x + w1.y) + (w1.z + w1.w);
                float fct = wm / lt;
#pragma unroll
                for (int t = 0; t < 8; ++t) mixed[t][j] += acc[t][j] * fct;
            }
        }
        __builtin_amdgcn_sched_barrier(0);
        af_cur = af_nxt;
    }

    __syncthreads();

#pragma unroll
    for (int t = 0; t < 8; ++t)
#pragma unroll
        for (int j = 0; j < 4; ++j)
            tr[ti * 16 + quad * 4 + j][w8 * 128 + t * 16 + lq] = f2bf(mixed[t][j]);
    __syncthreads();

    const unsigned short* VFn = VF + (size_t)n * CDIM * PKV;
    f32x4 accpv[2][2];
#pragma unroll
    for (int oi = 0; oi < 2; ++oi)
#pragma unroll
        for (int t2 = 0; t2 < 2; ++t2) accpv[oi][t2] = (f32x4){0.f, 0.f, 0.f, 0.f};
    bool has2 = (wv < 2);
#pragma unroll 4
    for (int pc = 0; pc < 32; ++pc) {
        bf16x8 pf0 = *(const bf16x8*)&tr[lq][pc * 32 + quad * 8];
        bf16x8 pf1 = *(const bf16x8*)&tr[16 + lq][pc * 32 + quad * 8];
        bf16x8 vf0 = *(const bf16x8*)(VFn + (size_t)(wv * 32 + pc) * 512 + lane * 8);
        accpv[0][0] = __builtin_amdgcn_mfma_f32_16x16x32_bf16(pf0, vf0, accpv[0][0], 0, 0, 0);
        accpv[0][1] = __builtin_amdgcn_mfma_f32_16x16x32_bf16(pf1, vf0, accpv[0][1], 0, 0, 0);
        if (has2) {
            bf16x8 vf1 = *(const bf16x8*)(VFn + (size_t)((wv + 16) * 32 + pc) * 512 + lane * 8);
            accpv[1][0] = __builtin_amdgcn_mfma_f32_16x16x32_bf16(pf0, vf1, accpv[1][0], 0, 0, 0);
            accpv[1][1] = __builtin_amdgcn_mfma_f32_16x16x32_bf16(pf1, vf1, accpv[1][1], 0, 0, 0);
        }
    }
    __syncthreads();

#pragma unroll
    for (int oi = 0; oi < 2; ++oi) {
        if (oi == 1 && !has2) continue;
        int ot = wv + oi * 16;
#pragma unroll
        for (int t2 = 0; t2 < 2; ++t2)
#pragma unroll
            for (int r = 0; r < 4; ++r)
                Mt[t2 * 16 + quad * 4 + r][ot * 16 + lq] = f2bf(accpv[oi][t2][r]);
    }
    __syncthreads();

    float g = gamma[0];
#pragma unroll
    for (int idx = 0; idx < 3; ++idx) {
        int ot = w8 + idx * 8;
        if (ot >= 18) continue;
        f32x4 acco = (f32x4){0.f, 0.f, 0.f, 0.f};
#pragma unroll
        for (int cc = 0; cc < 9; ++cc) {
            bf16x8 af = *(const bf16x8*)(WFp + (size_t)(ot * 9 + cc) * 512 + lane * 8);
            bf16x8 bfm = *(const bf16x8*)&Mt[ti * 16 + lq][cc * 32 + quad * 8];
            acco = __builtin_amdgcn_mfma_f32_16x16x32_bf16(af, bfm, acco, 0, 0, 0);
        }
#pragma unroll
        for (int r = 0; r < 4; ++r) {
            int o = ot * 16 + quad * 4 + r;
            size_t id = ((size_t)(n * CDIM) + o) * HW + it0 + lq;
            OUT[id] = g * (acco[r] + bproj[o]) + x[id];
        }
    }
}

// ---------------------------------------------------------------------------
extern "C" void kernel_launch(void* const* d_in, const int* in_sizes, int n_in,
                              void* d_out, int out_size, void* d_ws, size_t ws_size,
                              hipStream_t stream) {
    const float* x     = (const float*)d_in[0];
    const float* Wq    = (const float*)d_in[1];
    const float* Wk    = (const float*)d_in[2];
    const float* Wv    = (const float*)d_in[3];
    const float* Wx    = (const float*)d_in[4];
    const float* Wy    = (const float*)d_in[5];
    const float* Wproj = (const float*)d_in[6];
    const float* bproj = (const float*)d_in[7];
    const float* Wc    = (const float*)d_in[8];
    const float* bc    = (const float*)d_in[9];
    const float* gamma = (const float*)d_in[10];
    float* out = (float*)d_out;

    float* ws = (float*)d_ws;
    size_t off = 0;
    unsigned short* Qf  = (unsigned short*)(ws + off); off += (size_t)NB * MHEAD * HW * 32 / 2;
    unsigned short* KF  = (unsigned short*)(ws + off); off += (size_t)NB * MHEAD * PKV * 32 / 2;
    unsigned short* VF  = (unsigned short*)(ws + off); off += (size_t)NB * CDIM * PKV / 2;
    unsigned short* WFq = (unsigned short*)(ws + off); off += (size_t)CDIM * CDIM / 2;
    unsigned short* WFk = (unsigned short*)(ws + off); off += (size_t)CDIM * CDIM / 2;
    unsigned short* WFv = (unsigned short*)(ws + off); off += (size_t)CDIM * CDIM / 2;
    unsigned short* WFp = (unsigned short*)(ws + off); off += (size_t)CDIM * CDIM / 2;
    unsigned short* XF  = (unsigned short*)(ws + off); off += (size_t)NB * HW * CDIM / 2;
    unsigned short* FXb = (unsigned short*)(ws + off); off += (size_t)MHEAD * 8 * 512 / 2;
    unsigned short* FYb = (unsigned short*)(ws + off); off += (size_t)MHEAD * 8 * 512 / 2;
    float* MX   = ws + off; off += NB * CDIM;
    float* MIXW = ws + off; off += 32;

    prep<<<1314, 256, 0, stream>>>(x, Wq, Wk, Wv, Wproj,
                                   XF, WFq, WFk, WFv, WFp, MX);
    mid<<<973, 256, 0, stream>>>(Wx, Wy, FXb, FYb, Wq, MX, Wc, bc, MIXW,
                                 WFq, WFk, WFv, XF, Qf, KF, VF);
    attn_fused9<<<NB * HW / 32, 1024, 0, stream>>>(Qf, KF, VF, WFp, FXb, FYb, MIXW,
                                                   bproj, x, gamma, out);
}

// Round 10
// 172.958 us; speedup vs baseline: 2.3652x; 1.0761x over previous
//
#include <hip/hip_runtime.h>
#include <math.h>

// n=2, C=288, h=w=64 -> hw=4096; kv stride 2 -> 32x32 -> pkv=1024; M=9 heads, d=32
#define NB     2
#define CDIM   288
#define HW     4096
#define PKV    1024
#define MHEAD  9
#define DHEAD  32

typedef __attribute__((ext_vector_type(8))) short bf16x8;
typedef __attribute__((ext_vector_type(4))) float f32x4;

#if __has_builtin(__builtin_amdgcn_exp2f)
#define EXP2(x) __builtin_amdgcn_exp2f(x)
#else
#define EXP2(x) exp2f(x)
#endif

__device__ inline unsigned short f2bf(float x) {
    unsigned int u = __float_as_uint(x);
    u = (u + 0x7fffu + ((u >> 16) & 1u)) >> 16;
    return (unsigned short)u;
}

// ---------------------------------------------------------------------------
// Fragment-major tile (16 rows r, 32 k): elem(r,k) = ((r&15)+16*(k>>3))*8 + (k&7)
//  WF (A-side, rows=o, k=c): tiles (ot,cc) -> (ot*9+cc)*512
//  XF (B-side, rows=j, k=c): per n, (jt,cc) -> (jt*9+cc)*512
//  KF (B-side, rows=p, k=d): per (n,m), pt -> pt*512
//  VF (B-side, rows=o, k=p): per n, (ot,pc) -> (ot*32+pc)*512
//  FXb/FYb (B-side, rows=dif[128 padded], k=d): per m, tile t -> (m*8+t)*512
//
// Round-9 lesson: nt-stores on producer outputs REGRESSED attn 62->77us
// (remote-dirty-L2 snoop is FASTER than the HBM/L3 clean path) -> plain stores.

// ---------------------------------------------------------------------------
// prep: xtransF (+fused X row-partial-sums, replacing the separate meanx pass)
//       + wcvtF + pff + F-pad.  pff/F-pad moved from mid (no prep dependency).
__global__ __launch_bounds__(256) void prep(const float* __restrict__ X,
        const float* __restrict__ Wq, const float* __restrict__ Wk,
        const float* __restrict__ Wv, const float* __restrict__ Wproj,
        const float* __restrict__ Wx, const float* __restrict__ Wy,
        unsigned short* __restrict__ XF, unsigned short* __restrict__ WFq,
        unsigned short* __restrict__ WFk, unsigned short* __restrict__ WFv,
        unsigned short* __restrict__ WFp, unsigned short* __restrict__ FXb,
        unsigned short* __restrict__ FYb, float* __restrict__ MXP) {
    __shared__ float t32[32][133];
    __shared__ float emb[144];
    int b = blockIdx.x;
    int tid = threadIdx.x;
    if (b < 576) {
        // ---- xtransF: 128j x 32c tile, float4 loads; fused row partial sums
        int bx = b % 32, by = (b / 32) % 9, n = b / 288;
        int j0 = bx * 128, c0 = by * 32;
        int c = tid >> 3, f = tid & 7;
        const float* src = &X[((size_t)n * CDIM + c0 + c) * HW + j0];
        float psum = 0.f;
#pragma unroll
        for (int l = 0; l < 4; ++l) {
            float4 v = *(const float4*)&src[(f + l * 8) * 4];
            *(float4*)&t32[c][(f + l * 8) * 4] = v;
            psum += (v.x + v.y) + (v.z + v.w);
        }
        // reduce over the 8 lanes sharing row c (tid = c*8+f, contiguous)
        psum += __shfl_xor(psum, 1, 64);
        psum += __shfl_xor(psum, 2, 64);
        psum += __shfl_xor(psum, 4, 64);
        if (f == 0) MXP[((size_t)n * CDIM + c0 + c) * 32 + bx] = psum;
        __syncthreads();
        int cc = c0 >> 5;
#pragma unroll
        for (int l = 0; l < 4; ++l) {
            int g = l * 256 + tid;           // 0..1023
            int s = g >> 7;                  // j-subtile 0..7
            int w = g & 127;
            int lane = w >> 1, e0 = (w & 1) * 4;
            int jl = s * 16 + (lane & 15);
            int cb = (lane >> 4) * 8 + e0;
            unsigned int w0 = f2bf(t32[cb + 0][jl]) | ((unsigned int)f2bf(t32[cb + 1][jl]) << 16);
            unsigned int w1 = f2bf(t32[cb + 2][jl]) | ((unsigned int)f2bf(t32[cb + 3][jl]) << 16);
            int jt = (j0 >> 4) + s;
            unsigned short* O = XF + (size_t)n * HW * CDIM + ((size_t)jt * 9 + cc) * 512 + lane * 8 + e0;
            uint2 pk = { w0, w1 };
            *(uint2*)O = pk;
        }
    } else if (b < 738) {
        // ---- wcvtF: 4 weight matrices -> fragment-major bf16
        int t = b - 576;                  // 162 tiles
        int sub = tid >> 6, lane = tid & 63;
        int ot = t / 9, cc = t % 9;
        const float* W = (sub == 0) ? Wq : (sub == 1) ? Wk : (sub == 2) ? Wv : Wproj;
        unsigned short* O = ((sub == 0) ? WFq : (sub == 1) ? WFk : (sub == 2) ? WFv : WFp)
                            + (size_t)t * 512;
        int o  = ot * 16 + (lane & 15);
        int c0 = cc * 32 + (lane >> 4) * 8;
        const float* src = W + (size_t)o * CDIM + c0;
        float4 f0 = *(const float4*)src, f1 = *(const float4*)(src + 4);
        unsigned int v0 = f2bf(f0.x) | ((unsigned int)f2bf(f0.y) << 16);
        unsigned int v1 = f2bf(f0.z) | ((unsigned int)f2bf(f0.w) << 16);
        unsigned int v2 = f2bf(f1.x) | ((unsigned int)f2bf(f1.y) << 16);
        unsigned int v3 = f2bf(f1.z) | ((unsigned int)f2bf(f1.w) << 16);
        uint4 pk = { v0, v1, v2, v3 };
        *(uint4*)(O + lane * 8) = pk;
    } else if (b < 990) {
        // ---- pff (moved from mid; depends only on Wx/Wy)
        int u = b - 738;                  // 252
        int axis = u / 126;
        int dif  = u % 126;
        float diff = (float)(dif - 62);
        if (tid < 72) {
            float dm = expf(6.9077552789821368f * ((float)tid * (1.f / 72.f)));
            float t  = diff / dm;
            emb[tid]      = sinf(t);
            emb[72 + tid] = cosf(t);
        }
        __syncthreads();
        const float* W = axis ? Wy : Wx;          // (288 x 144) row-major
        unsigned short* F = axis ? FYb : FXb;
        for (int o = tid; o < CDIM; o += 256) {
            const float* wr = W + (size_t)o * 144;
            float s = 0.f;
#pragma unroll 9
            for (int f4 = 0; f4 < 36; ++f4) {
                float4 w4 = *(const float4*)&wr[f4 * 4];
                s += emb[f4 * 4 + 0] * w4.x + emb[f4 * 4 + 1] * w4.y
                   + emb[f4 * 4 + 2] * w4.z + emb[f4 * 4 + 3] * w4.w;
            }
            int m = o >> 5, d = o & 31;
            F[(size_t)(m * 8 + (dif >> 4)) * 512 + ((dif & 15) + 16 * (d >> 3)) * 8 + (d & 7)]
                = f2bf(s * 0.70710678118654752f);
        }
    } else {
        // ---- F-table pad rows (dif = 126,127) -> zero
        for (int idx = tid; idx < 1152; idx += 256) {
            int d = idx & 31, rr = (idx >> 5) & 1, mm = (idx >> 6) % 9, ax = idx / 576;
            int dif = 126 + rr;
            unsigned short* F = ax ? FYb : FXb;
            F[(size_t)(mm * 8 + 7) * 512 + ((dif & 15) + 16 * (d >> 3)) * 8 + (d & 7)] = 0;
        }
    }
}

// ---------------------------------------------------------------------------
// mid: mixw (from MXP partials) + qkv.  Qf pre-scaled by log2(e).
__global__ __launch_bounds__(256) void mid(
        const float* __restrict__ Wq, const float* __restrict__ MXP,
        const float* __restrict__ Wc, const float* __restrict__ bc,
        float* __restrict__ MIXW,
        const unsigned short* __restrict__ WFq, const unsigned short* __restrict__ WFk,
        const unsigned short* __restrict__ WFv, const unsigned short* __restrict__ XF,
        unsigned short* __restrict__ Qf, unsigned short* __restrict__ KF,
        unsigned short* __restrict__ VF) {
    __shared__ float mxs[NB * CDIM];
    __shared__ float ctx_s[NB * CDIM];
    __shared__ float lg[18];
    __shared__ __attribute__((aligned(16))) unsigned short tr[4][32][40];
    int b = blockIdx.x;
    int tid = threadIdx.x;

    if (b == 0) {
        // ---- mixw: reconstruct row means from 32 partials, then softmax mix
        for (int idx = tid; idx < NB * CDIM; idx += 256) {
            const float* pp = &MXP[(size_t)idx * 32];
            float s = 0.f;
#pragma unroll
            for (int k = 0; k < 32; k += 4) {
                float4 v = *(const float4*)&pp[k];
                s += (v.x + v.y) + (v.z + v.w);
            }
            mxs[idx] = s * (1.f / 4096.f);
        }
        __syncthreads();
        for (int p = tid; p < NB * CDIM; p += 256) {
            int n = p / CDIM, o = p % CDIM;
            const float* wr = Wq + (size_t)o * CDIM;
            const float* mx = &mxs[n * CDIM];
            float s = 0.f;
            for (int c = 0; c < CDIM; c += 4) {
                float4 w4 = *(const float4*)&wr[c];
                float4 m4 = *(const float4*)&mx[c];
                s += w4.x * m4.x + w4.y * m4.y + w4.z * m4.z + w4.w * m4.w;
            }
            ctx_s[p] = s;
        }
        __syncthreads();
        if (tid < 18) {
            int n = tid / 9, j = tid % 9;
            float s = bc[j];
            for (int o = 0; o < CDIM; ++o) s += ctx_s[n * CDIM + o] * Wc[j * CDIM + o];
            lg[tid] = s;
        }
        __syncthreads();
        if (tid < 2) {
            float mx = -1e30f;
            for (int j = 0; j < 9; ++j) mx = fmaxf(mx, lg[tid * 9 + j]);
            float e[9], sm = 0.f;
            for (int j = 0; j < 9; ++j) { e[j] = __expf(lg[tid * 9 + j] - mx); sm += e[j]; }
            for (int j = 0; j < 9; ++j) MIXW[tid * 9 + j] = e[j] / sm;
        }
    } else {
        int bx = b - 1;                   // 720 qkv blocks
        int gx = bx % 40;
        int m  = (bx / 40) % 9;
        int n  = bx / 360;
        int wv = tid >> 6, lane = tid & 63;
        int lq = lane & 15, quad = lane >> 4;
        if (gx < 32) {
            int j0 = gx * 128;
            int jw = j0 + wv * 32;
            const unsigned short* Wb = WFq + ((size_t)(m * 2) * 9) * 512 + lane * 8;
            const unsigned short* Xb = XF + (size_t)n * HW * CDIM + ((size_t)(jw >> 4) * 9) * 512 + lane * 8;
            f32x4 acc[2][2] = {};
#pragma unroll
            for (int cc = 0; cc < 9; ++cc) {
                bf16x8 a0 = *(const bf16x8*)(Wb + (size_t)cc * 512);
                bf16x8 a1 = *(const bf16x8*)(Wb + (size_t)(9 + cc) * 512);
                bf16x8 b0 = *(const bf16x8*)(Xb + (size_t)cc * 512);
                bf16x8 b1 = *(const bf16x8*)(Xb + (size_t)(9 + cc) * 512);
                acc[0][0] = __builtin_amdgcn_mfma_f32_16x16x32_bf16(a0, b0, acc[0][0], 0, 0, 0);
                acc[0][1] = __builtin_amdgcn_mfma_f32_16x16x32_bf16(a0, b1, acc[0][1], 0, 0, 0);
                acc[1][0] = __builtin_amdgcn_mfma_f32_16x16x32_bf16(a1, b0, acc[1][0], 0, 0, 0);
                acc[1][1] = __builtin_amdgcn_mfma_f32_16x16x32_bf16(a1, b1, acc[1][1], 0, 0, 0);
            }
#pragma unroll
            for (int oi = 0; oi < 2; ++oi)
#pragma unroll
                for (int ji = 0; ji < 2; ++ji)
#pragma unroll
                    for (int r = 0; r < 4; ++r)
                        tr[wv][ji * 16 + lq][oi * 16 + quad * 4 + r]
                            = f2bf(1.4426950408889634f * acc[oi][ji][r]);   // log2(e) pre-scale
            int jl = lane & 31, half = lane >> 5;
            bf16x8 v0 = *(const bf16x8*)&tr[wv][jl][half * 16];
            bf16x8 v1 = *(const bf16x8*)&tr[wv][jl][half * 16 + 8];
            unsigned short* Qm = Qf + ((size_t)(n * MHEAD + m) * HW + jw + jl) * 32 + half * 16;
            *(bf16x8*)Qm = v0;
            *(bf16x8*)(Qm + 8) = v1;
        } else {
            int p0 = (gx - 32) * 128;
            int pw = p0 + wv * 32;
            const unsigned short* XFn = XF + (size_t)n * HW * CDIM;
            size_t bidx[2];
#pragma unroll
            for (int pi = 0; pi < 2; ++pi) {
                int p   = pw + pi * 16 + lq;
                int pos = ((p >> 5) << 7) + ((p & 31) << 1);
                bidx[pi] = ((size_t)(pos >> 4) * 9) * 512 + ((pos & 15) + 16 * quad) * 8;
            }
            const unsigned short* Wkb = WFk + ((size_t)(m * 2) * 9) * 512 + lane * 8;
            const unsigned short* Wvb = WFv + ((size_t)(m * 2) * 9) * 512 + lane * 8;
            f32x4 ak[2][2] = {}, av[2][2] = {};
#pragma unroll
            for (int cc = 0; cc < 9; ++cc) {
                bf16x8 a0k = *(const bf16x8*)(Wkb + (size_t)cc * 512);
                bf16x8 a1k = *(const bf16x8*)(Wkb + (size_t)(9 + cc) * 512);
                bf16x8 a0v = *(const bf16x8*)(Wvb + (size_t)cc * 512);
                bf16x8 a1v = *(const bf16x8*)(Wvb + (size_t)(9 + cc) * 512);
                bf16x8 b0  = *(const bf16x8*)(XFn + bidx[0] + (size_t)cc * 512);
                bf16x8 b1  = *(const bf16x8*)(XFn + bidx[1] + (size_t)cc * 512);
                ak[0][0] = __builtin_amdgcn_mfma_f32_16x16x32_bf16(a0k, b0, ak[0][0], 0, 0, 0);
                ak[0][1] = __builtin_amdgcn_mfma_f32_16x16x32_bf16(a0k, b1, ak[0][1], 0, 0, 0);
                ak[1][0] = __builtin_amdgcn_mfma_f32_16x16x32_bf16(a1k, b0, ak[1][0], 0, 0, 0);
                ak[1][1] = __builtin_amdgcn_mfma_f32_16x16x32_bf16(a1k, b1, ak[1][1], 0, 0, 0);
                av[0][0] = __builtin_amdgcn_mfma_f32_16x16x32_bf16(a0v, b0, av[0][0], 0, 0, 0);
                av[0][1] = __builtin_amdgcn_mfma_f32_16x16x32_bf16(a0v, b1, av[0][1], 0, 0, 0);
                av[1][0] = __builtin_amdgcn_mfma_f32_16x16x32_bf16(a1v, b0, av[1][0], 0, 0, 0);
                av[1][1] = __builtin_amdgcn_mfma_f32_16x16x32_bf16(a1v, b1, av[1][1], 0, 0, 0);
            }
#pragma unroll
            for (int oi = 0; oi < 2; ++oi)
#pragma unroll
                for (int pi = 0; pi < 2; ++pi)
#pragma unroll
                    for (int r = 0; r < 4; ++r)
                        tr[wv][pi * 16 + lq][oi * 16 + quad * 4 + r] = f2bf(ak[oi][pi][r]);
            unsigned short* KFm = KF + (size_t)(n * MHEAD + m) * (PKV * 32);
#pragma unroll
            for (int pi = 0; pi < 2; ++pi) {
                bf16x8 v = *(const bf16x8*)&tr[wv][pi * 16 + lq][quad * 8];
                *(bf16x8*)(KFm + (size_t)((pw >> 4) + pi) * 512 + lane * 8) = v;
            }
#pragma unroll
            for (int oi = 0; oi < 2; ++oi)
#pragma unroll
                for (int pi = 0; pi < 2; ++pi)
#pragma unroll
                    for (int r = 0; r < 4; ++r)
                        tr[wv][oi * 16 + quad * 4 + r][pi * 16 + lq] = f2bf(av[oi][pi][r]);
            unsigned short* VFn = VF + (size_t)n * CDIM * PKV;
#pragma unroll
            for (int oi = 0; oi < 2; ++oi) {
                bf16x8 v = *(const bf16x8*)&tr[wv][oi * 16 + lq][quad * 8];
                *(bf16x8*)(VFn + (size_t)((m * 2 + oi) * 32 + (pw >> 5)) * 512 + lane * 8) = v;
            }
        }
    }
}

// ---------------------------------------------------------------------------
// attn_fused10: round-3 fused7 body verbatim (verified best: 61.9us).
__global__ __launch_bounds__(1024, 4) void attn_fused10(
        const unsigned short* __restrict__ Qf, const unsigned short* __restrict__ KF,
        const unsigned short* __restrict__ VF, const unsigned short* __restrict__ WFp,
        const unsigned short* __restrict__ FXb, const unsigned short* __restrict__ FYb,
        const float* __restrict__ MIXW, const float* __restrict__ bproj,
        const float* __restrict__ x, const float* __restrict__ gamma,
        float* __restrict__ OUT) {
    int n    = blockIdx.x >> 7;          // 256 blocks
    int i0   = (blockIdx.x & 127) * 32;  // 32 q-rows per block
    int tid  = threadIdx.x;
    int wv   = tid >> 6;                 // 0..15
    int ti   = wv >> 3;                  // i-tile 0/1
    int w8   = wv & 7;                   // kv-slice / role within tile-group
    int lane = tid & 63;
    int lq   = lane & 15;
    int quad = lane >> 4;
    int it0  = i0 + ti * 16;

    int bx_t = (it0 & 63) >> 4;
    int hh   = i0 >> 6;
    int by_t = hh >> 4;
    int dh   = hh & 15;

    __shared__ __attribute__((aligned(16))) unsigned short tr[32][1032];
    float (*Rx_s)[2][16][82] = reinterpret_cast<float (*)[2][16][82]>((char*)&tr[0][0]);
    float (*Ry_s)[2][16][82] = reinterpret_cast<float (*)[2][16][82]>((char*)&tr[0][0] + 20992);
    float (*ws_s)[2][16][8]  = reinterpret_cast<float (*)[2][16][8]>((char*)&tr[0][0] + 41984);
    unsigned short (*Mt)[296] = reinterpret_cast<unsigned short (*)[296]>(&tr[0][0]);

    float mixed[8][4];
#pragma unroll
    for (int t = 0; t < 8; ++t)
#pragma unroll
        for (int j = 0; j < 4; ++j) mixed[t][j] = 0.f;

    auto r_phase = [&](int mm, bf16x8 af) {
        int pp = mm & 1;
        if (w8 < 5) {
            bf16x8 bR = *(const bf16x8*)(FXb + (size_t)(mm * 8 + bx_t + w8) * 512 + lane * 8);
            f32x4 r = (f32x4){0.f, 0.f, 0.f, 0.f};
            r = __builtin_amdgcn_mfma_f32_16x16x32_bf16(af, bR, r, 0, 0, 0);
#pragma unroll
            for (int reg = 0; reg < 4; ++reg)
                Rx_s[pp][ti][quad * 4 + reg][w8 * 16 + lq] = r[reg];
        } else {
            bf16x8 bR = *(const bf16x8*)(FYb + (size_t)(mm * 8 + by_t + (w8 - 5)) * 512 + lane * 8);
            f32x4 r = (f32x4){0.f, 0.f, 0.f, 0.f};
            r = __builtin_amdgcn_mfma_f32_16x16x32_bf16(af, bR, r, 0, 0, 0);
#pragma unroll
            for (int reg = 0; reg < 4; ++reg)
                Ry_s[pp][ti][quad * 4 + reg][(w8 - 5) * 16 + lq] = r[reg];
        }
        if (w8 < 2) {
            bf16x8 bR = *(const bf16x8*)(FYb + (size_t)(mm * 8 + by_t + 3 + w8) * 512 + lane * 8);
            f32x4 r = (f32x4){0.f, 0.f, 0.f, 0.f};
            r = __builtin_amdgcn_mfma_f32_16x16x32_bf16(af, bR, r, 0, 0, 0);
#pragma unroll
            for (int reg = 0; reg < 4; ++reg)
                Ry_s[pp][ti][quad * 4 + reg][(3 + w8) * 16 + lq] = r[reg];
        }
    };

    bf16x8 af_cur = *(const bf16x8*)(Qf + (((size_t)n * MHEAD) * HW + it0 + lq) * 32 + quad * 8);
    r_phase(0, af_cur);
    __syncthreads();

#pragma unroll 1
    for (int m = 0; m < MHEAD; ++m) {
        const unsigned short* KmF = KF + (size_t)(n * MHEAD + m) * (PKV * 32);
        bf16x8 kf[8];
#pragma unroll
        for (int t = 0; t < 8; ++t)
            kf[t] = *(const bf16x8*)(KmF + (size_t)(w8 * 8 + t) * 512 + lane * 8);

        bf16x8 af_nxt = af_cur;
        __builtin_amdgcn_s_setprio(1);
        if (m + 1 < MHEAD) {
            af_nxt = *(const bf16x8*)(Qf + (((size_t)(n * MHEAD + m + 1)) * HW + it0 + lq) * 32 + quad * 8);
            r_phase(m + 1, af_nxt);
        }
        f32x4 acc[8];
#pragma unroll
        for (int t = 0; t < 8; ++t) {
            f32x4 z = (f32x4){0.f, 0.f, 0.f, 0.f};
            acc[t] = __builtin_amdgcn_mfma_f32_16x16x32_bf16(af_cur, kf[t], z, 0, 0, 0);
        }
        __builtin_amdgcn_s_setprio(0);

        int par = m & 1;
        float exA[4], exB[4];
#pragma unroll
        for (int j = 0; j < 4; ++j) {
            int q = quad * 4 + j;
            exA[j] = Rx_s[par][ti][q][q + 62 - 2 * lq];
            exB[j] = Rx_s[par][ti][q][q + 30 - 2 * lq];
        }
        float rs[4] = {0.f, 0.f, 0.f, 0.f};
#pragma unroll
        for (int tp = 0; tp < 4; ++tp) {
            int u = w8 * 4 + tp;
            float ey[4];
#pragma unroll
            for (int j = 0; j < 4; ++j) ey[j] = Ry_s[par][ti][quad * 4 + j][dh + 62 - 2 * u];
#pragma unroll
            for (int half = 0; half < 2; ++half) {
                int t = tp * 2 + half;
#pragma unroll
                for (int j = 0; j < 4; ++j) {
                    float e = EXP2(acc[t][j] + (half ? exB[j] : exA[j]) + ey[j]);
                    rs[j] += e;
                    acc[t][j] = e;
                }
            }
        }
#pragma unroll
        for (int j = 0; j < 4; ++j) {
            rs[j] += __shfl_xor(rs[j], 1, 64);
            rs[j] += __shfl_xor(rs[j], 2, 64);
            rs[j] += __shfl_xor(rs[j], 4, 64);
            rs[j] += __shfl_xor(rs[j], 8, 64);
        }
        if (lq == 0) {
#pragma unroll
            for (int j = 0; j < 4; ++j) ws_s[par][ti][quad * 4 + j][w8] = rs[j];
        }
        __syncthreads();

        {
            float wm = MIXW[n * MHEAD + m];
#pragma unroll
            for (int j = 0; j < 4; ++j) {
                int q = quad * 4 + j;
                float4 w0 = *(const float4*)&ws_s[par][ti][q][0];
                float4 w1 = *(const float4*)&ws_s[par][ti][q][4];
                float lt = (w0.x + w0.y) + (w0.z + w0.w) + (w1.x + w1.y) + (w1.z + w1.w);
                float fct = wm / lt;
#pragma unroll
                for (int t = 0; t < 8; ++t) mixed[t][j] += acc[t][j] * fct;
            }
        }
        __builtin_amdgcn_sched_barrier(0);
        af_cur = af_nxt;
    }

    __syncthreads();

#pragma unroll
    for (int t = 0; t < 8; ++t)
#pragma unroll
        for (int j = 0; j < 4; ++j)
            tr[ti * 16 + quad * 4 + j][w8 * 128 + t * 16 + lq] = f2bf(mixed[t][j]);
    __syncthreads();

    const unsigned short* VFn = VF + (size_t)n * CDIM * PKV;
    f32x4 accpv[2][2];
#pragma unroll
    for (int oi = 0; oi < 2; ++oi)
#pragma unroll
        for (int t2 = 0; t2 < 2; ++t2) accpv[oi][t2] = (f32x4){0.f, 0.f, 0.f, 0.f};
    bool has2 = (wv < 2);
#pragma unroll 4
    for (int pc = 0; pc < 32; ++pc) {
        bf16x8 pf0 = *(const bf16x8*)&tr[lq][pc * 32 + quad * 8];
        bf16x8 pf1 = *(const bf16x8*)&tr[16 + lq][pc * 32 + quad * 8];
        bf16x8 vf0 = *(const bf16x8*)(VFn + (size_t)(wv * 32 + pc) * 512 + lane * 8);
        accpv[0][0] = __builtin_amdgcn_mfma_f32_16x16x32_bf16(pf0, vf0, accpv[0][0], 0, 0, 0);
        accpv[0][1] = __builtin_amdgcn_mfma_f32_16x16x32_bf16(pf1, vf0, accpv[0][1], 0, 0, 0);
        if (has2) {
            bf16x8 vf1 = *(const bf16x8*)(VFn + (size_t)((wv + 16) * 32 + pc) * 512 + lane * 8);
            accpv[1][0] = __builtin_amdgcn_mfma_f32_16x16x32_bf16(pf0, vf1, accpv[1][0], 0, 0, 0);
            accpv[1][1] = __builtin_amdgcn_mfma_f32_16x16x32_bf16(pf1, vf1, accpv[1][1], 0, 0, 0);
        }
    }
    __syncthreads();

#pragma unroll
    for (int oi = 0; oi < 2; ++oi) {
        if (oi == 1 && !has2) continue;
        int ot = wv + oi * 16;
#pragma unroll
        for (int t2 = 0; t2 < 2; ++t2)
#pragma unroll
            for (int r = 0; r < 4; ++r)
                Mt[t2 * 16 + quad * 4 + r][ot * 16 + lq] = f2bf(accpv[oi][t2][r]);
    }
    __syncthreads();

    float g = gamma[0];
#pragma unroll
    for (int idx = 0; idx < 3; ++idx) {
        int ot = w8 + idx * 8;
        if (ot >= 18) continue;
        f32x4 acco = (f32x4){0.f, 0.f, 0.f, 0.f};
#pragma unroll
        for (int cc = 0; cc < 9; ++cc) {
            bf16x8 af = *(const bf16x8*)(WFp + (size_t)(ot * 9 + cc) * 512 + lane * 8);
            bf16x8 bfm = *(const bf16x8*)&Mt[ti * 16 + lq][cc * 32 + quad * 8];
            acco = __builtin_amdgcn_mfma_f32_16x16x32_bf16(af, bfm, acco, 0, 0, 0);
        }
#pragma unroll
        for (int r = 0; r < 4; ++r) {
            int o = ot * 16 + quad * 4 + r;
            size_t id = ((size_t)(n * CDIM) + o) * HW + it0 + lq;
            OUT[id] = g * (acco[r] + bproj[o]) + x[id];
        }
    }
}

// ---------------------------------------------------------------------------
extern "C" void kernel_launch(void* const* d_in, const int* in_sizes, int n_in,
                              void* d_out, int out_size, void* d_ws, size_t ws_size,
                              hipStream_t stream) {
    const float* x     = (const float*)d_in[0];
    const float* Wq    = (const float*)d_in[1];
    const float* Wk    = (const float*)d_in[2];
    const float* Wv    = (const float*)d_in[3];
    const float* Wx    = (const float*)d_in[4];
    const float* Wy    = (const float*)d_in[5];
    const float* Wproj = (const float*)d_in[6];
    const float* bproj = (const float*)d_in[7];
    const float* Wc    = (const float*)d_in[8];
    const float* bc    = (const float*)d_in[9];
    const float* gamma = (const float*)d_in[10];
    float* out = (float*)d_out;

    float* ws = (float*)d_ws;
    size_t off = 0;
    unsigned short* Qf  = (unsigned short*)(ws + off); off += (size_t)NB * MHEAD * HW * 32 / 2;
    unsigned short* KF  = (unsigned short*)(ws + off); off += (size_t)NB * MHEAD * PKV * 32 / 2;
    unsigned short* VF  = (unsigned short*)(ws + off); off += (size_t)NB * CDIM * PKV / 2;
    unsigned short* WFq = (unsigned short*)(ws + off); off += (size_t)CDIM * CDIM / 2;
    unsigned short* WFk = (unsigned short*)(ws + off); off += (size_t)CDIM * CDIM / 2;
    unsigned short* WFv = (unsigned short*)(ws + off); off += (size_t)CDIM * CDIM / 2;
    unsigned short* WFp = (unsigned short*)(ws + off); off += (size_t)CDIM * CDIM / 2;
    unsigned short* XF  = (unsigned short*)(ws + off); off += (size_t)NB * HW * CDIM / 2;
    unsigned short* FXb = (unsigned short*)(ws + off); off += (size_t)MHEAD * 8 * 512 / 2;
    unsigned short* FYb = (unsigned short*)(ws + off); off += (size_t)MHEAD * 8 * 512 / 2;
    float* MXP  = ws + off; off += (size_t)NB * CDIM * 32;
    float* MIXW = ws + off; off += 32;

    prep<<<991, 256, 0, stream>>>(x, Wq, Wk, Wv, Wproj, Wx, Wy,
                                  XF, WFq, WFk, WFv, WFp, FXb, FYb, MXP);
    mid<<<721, 256, 0, stream>>>(Wq, MXP, Wc, bc, MIXW,
                                 WFq, WFk, WFv, XF, Qf, KF, VF);
    attn_fused10<<<NB * HW / 32, 1024, 0, stream>>>(Qf, KF, VF, WFp, FXb, FYb, MIXW,
                                                    bproj, x, gamma, out);
}

// Round 11
// 170.888 us; speedup vs baseline: 2.3939x; 1.0121x over previous
//
#include <hip/hip_runtime.h>
#include <math.h>

// n=2, C=288, h=w=64 -> hw=4096; kv stride 2 -> 32x32 -> pkv=1024; M=9 heads, d=32
#define NB     2
#define CDIM   288
#define HW     4096
#define PKV    1024
#define MHEAD  9
#define DHEAD  32

typedef __attribute__((ext_vector_type(8))) short bf16x8;
typedef __attribute__((ext_vector_type(4))) float f32x4;

#if __has_builtin(__builtin_amdgcn_exp2f)
#define EXP2(x) __builtin_amdgcn_exp2f(x)
#else
#define EXP2(x) exp2f(x)
#endif

__device__ inline unsigned short f2bf(float x) {
    unsigned int u = __float_as_uint(x);
    u = (u + 0x7fffu + ((u >> 16) & 1u)) >> 16;
    return (unsigned short)u;
}

// ---------------------------------------------------------------------------
// Fragment-major tile (16 rows r, 32 k): elem(r,k) = ((r&15)+16*(k>>3))*8 + (k&7)
//  WF (A-side, rows=o, k=c): tiles (ot,cc) -> (ot*9+cc)*512
//  XF (B-side, rows=j, k=c): per n, (jt,cc) -> (jt*9+cc)*512
//  KF (B-side, rows=p, k=d): per (n,m), pt -> pt*512
//  VF (B-side, rows=o, k=p): per n, (ot,pc) -> (ot*32+pc)*512
//  FXb/FYb (B-side, rows=dif[128 padded], k=d): per m, tile t -> (m*8+t)*512
//
// Round-9 lesson: nt-stores on producer outputs REGRESSED attn 62->77us
// (remote-dirty-L2 snoop is FASTER than the HBM/L3 clean path) -> plain stores.

// ---------------------------------------------------------------------------
// prep: xtransF (+fused X row-partial-sums) + wcvtF + pff + F-pad.
__global__ __launch_bounds__(256) void prep(const float* __restrict__ X,
        const float* __restrict__ Wq, const float* __restrict__ Wk,
        const float* __restrict__ Wv, const float* __restrict__ Wproj,
        const float* __restrict__ Wx, const float* __restrict__ Wy,
        unsigned short* __restrict__ XF, unsigned short* __restrict__ WFq,
        unsigned short* __restrict__ WFk, unsigned short* __restrict__ WFv,
        unsigned short* __restrict__ WFp, unsigned short* __restrict__ FXb,
        unsigned short* __restrict__ FYb, float* __restrict__ MXP) {
    __shared__ float t32[32][133];
    __shared__ float emb[144];
    int b = blockIdx.x;
    int tid = threadIdx.x;
    if (b < 576) {
        // ---- xtransF: 128j x 32c tile, float4 loads; fused row partial sums
        int bx = b % 32, by = (b / 32) % 9, n = b / 288;
        int j0 = bx * 128, c0 = by * 32;
        int c = tid >> 3, f = tid & 7;
        const float* src = &X[((size_t)n * CDIM + c0 + c) * HW + j0];
        float psum = 0.f;
#pragma unroll
        for (int l = 0; l < 4; ++l) {
            float4 v = *(const float4*)&src[(f + l * 8) * 4];
            *(float4*)&t32[c][(f + l * 8) * 4] = v;
            psum += (v.x + v.y) + (v.z + v.w);
        }
        psum += __shfl_xor(psum, 1, 64);
        psum += __shfl_xor(psum, 2, 64);
        psum += __shfl_xor(psum, 4, 64);
        if (f == 0) MXP[((size_t)n * CDIM + c0 + c) * 32 + bx] = psum;
        __syncthreads();
        int cc = c0 >> 5;
#pragma unroll
        for (int l = 0; l < 4; ++l) {
            int g = l * 256 + tid;           // 0..1023
            int s = g >> 7;                  // j-subtile 0..7
            int w = g & 127;
            int lane = w >> 1, e0 = (w & 1) * 4;
            int jl = s * 16 + (lane & 15);
            int cb = (lane >> 4) * 8 + e0;
            unsigned int w0 = f2bf(t32[cb + 0][jl]) | ((unsigned int)f2bf(t32[cb + 1][jl]) << 16);
            unsigned int w1 = f2bf(t32[cb + 2][jl]) | ((unsigned int)f2bf(t32[cb + 3][jl]) << 16);
            int jt = (j0 >> 4) + s;
            unsigned short* O = XF + (size_t)n * HW * CDIM + ((size_t)jt * 9 + cc) * 512 + lane * 8 + e0;
            uint2 pk = { w0, w1 };
            *(uint2*)O = pk;
        }
    } else if (b < 738) {
        // ---- wcvtF: 4 weight matrices -> fragment-major bf16
        int t = b - 576;                  // 162 tiles
        int sub = tid >> 6, lane = tid & 63;
        int ot = t / 9, cc = t % 9;
        const float* W = (sub == 0) ? Wq : (sub == 1) ? Wk : (sub == 2) ? Wv : Wproj;
        unsigned short* O = ((sub == 0) ? WFq : (sub == 1) ? WFk : (sub == 2) ? WFv : WFp)
                            + (size_t)t * 512;
        int o  = ot * 16 + (lane & 15);
        int c0 = cc * 32 + (lane >> 4) * 8;
        const float* src = W + (size_t)o * CDIM + c0;
        float4 f0 = *(const float4*)src, f1 = *(const float4*)(src + 4);
        unsigned int v0 = f2bf(f0.x) | ((unsigned int)f2bf(f0.y) << 16);
        unsigned int v1 = f2bf(f0.z) | ((unsigned int)f2bf(f0.w) << 16);
        unsigned int v2 = f2bf(f1.x) | ((unsigned int)f2bf(f1.y) << 16);
        unsigned int v3 = f2bf(f1.z) | ((unsigned int)f2bf(f1.w) << 16);
        uint4 pk = { v0, v1, v2, v3 };
        *(uint4*)(O + lane * 8) = pk;
    } else if (b < 990) {
        // ---- pff (depends only on Wx/Wy)
        int u = b - 738;                  // 252
        int axis = u / 126;
        int dif  = u % 126;
        float diff = (float)(dif - 62);
        if (tid < 72) {
            float dm = expf(6.9077552789821368f * ((float)tid * (1.f / 72.f)));
            float t  = diff / dm;
            emb[tid]      = sinf(t);
            emb[72 + tid] = cosf(t);
        }
        __syncthreads();
        const float* W = axis ? Wy : Wx;          // (288 x 144) row-major
        unsigned short* F = axis ? FYb : FXb;
        for (int o = tid; o < CDIM; o += 256) {
            const float* wr = W + (size_t)o * 144;
            float s = 0.f;
#pragma unroll 9
            for (int f4 = 0; f4 < 36; ++f4) {
                float4 w4 = *(const float4*)&wr[f4 * 4];
                s += emb[f4 * 4 + 0] * w4.x + emb[f4 * 4 + 1] * w4.y
                   + emb[f4 * 4 + 2] * w4.z + emb[f4 * 4 + 3] * w4.w;
            }
            int m = o >> 5, d = o & 31;
            F[(size_t)(m * 8 + (dif >> 4)) * 512 + ((dif & 15) + 16 * (d >> 3)) * 8 + (d & 7)]
                = f2bf(s * 0.70710678118654752f);
        }
    } else {
        // ---- F-table pad rows (dif = 126,127) -> zero
        for (int idx = tid; idx < 1152; idx += 256) {
            int d = idx & 31, rr = (idx >> 5) & 1, mm = (idx >> 6) % 9, ax = idx / 576;
            int dif = 126 + rr;
            unsigned short* F = ax ? FYb : FXb;
            F[(size_t)(mm * 8 + 7) * 512 + ((dif & 15) + 16 * (d >> 3)) * 8 + (d & 7)] = 0;
        }
    }
}

// ---------------------------------------------------------------------------
// mid: mixw (from MXP partials) + qkv.  Qf pre-scaled by log2(e).
__global__ __launch_bounds__(256) void mid(
        const float* __restrict__ Wq, const float* __restrict__ MXP,
        const float* __restrict__ Wc, const float* __restrict__ bc,
        float* __restrict__ MIXW,
        const unsigned short* __restrict__ WFq, const unsigned short* __restrict__ WFk,
        const unsigned short* __restrict__ WFv, const unsigned short* __restrict__ XF,
        unsigned short* __restrict__ Qf, unsigned short* __restrict__ KF,
        unsigned short* __restrict__ VF) {
    __shared__ float mxs[NB * CDIM];
    __shared__ float ctx_s[NB * CDIM];
    __shared__ float lg[18];
    __shared__ __attribute__((aligned(16))) unsigned short tr[4][32][40];
    int b = blockIdx.x;
    int tid = threadIdx.x;

    if (b == 0) {
        for (int idx = tid; idx < NB * CDIM; idx += 256) {
            const float* pp = &MXP[(size_t)idx * 32];
            float s = 0.f;
#pragma unroll
            for (int k = 0; k < 32; k += 4) {
                float4 v = *(const float4*)&pp[k];
                s += (v.x + v.y) + (v.z + v.w);
            }
            mxs[idx] = s * (1.f / 4096.f);
        }
        __syncthreads();
        for (int p = tid; p < NB * CDIM; p += 256) {
            int n = p / CDIM, o = p % CDIM;
            const float* wr = Wq + (size_t)o * CDIM;
            const float* mx = &mxs[n * CDIM];
            float s = 0.f;
            for (int c = 0; c < CDIM; c += 4) {
                float4 w4 = *(const float4*)&wr[c];
                float4 m4 = *(const float4*)&mx[c];
                s += w4.x * m4.x + w4.y * m4.y + w4.z * m4.z + w4.w * m4.w;
            }
            ctx_s[p] = s;
        }
        __syncthreads();
        if (tid < 18) {
            int n = tid / 9, j = tid % 9;
            float s = bc[j];
            for (int o = 0; o < CDIM; ++o) s += ctx_s[n * CDIM + o] * Wc[j * CDIM + o];
            lg[tid] = s;
        }
        __syncthreads();
        if (tid < 2) {
            float mx = -1e30f;
            for (int j = 0; j < 9; ++j) mx = fmaxf(mx, lg[tid * 9 + j]);
            float e[9], sm = 0.f;
            for (int j = 0; j < 9; ++j) { e[j] = __expf(lg[tid * 9 + j] - mx); sm += e[j]; }
            for (int j = 0; j < 9; ++j) MIXW[tid * 9 + j] = e[j] / sm;
        }
    } else {
        int bx = b - 1;                   // 720 qkv blocks
        int gx = bx % 40;
        int m  = (bx / 40) % 9;
        int n  = bx / 360;
        int wv = tid >> 6, lane = tid & 63;
        int lq = lane & 15, quad = lane >> 4;
        if (gx < 32) {
            int j0 = gx * 128;
            int jw = j0 + wv * 32;
            const unsigned short* Wb = WFq + ((size_t)(m * 2) * 9) * 512 + lane * 8;
            const unsigned short* Xb = XF + (size_t)n * HW * CDIM + ((size_t)(jw >> 4) * 9) * 512 + lane * 8;
            f32x4 acc[2][2] = {};
#pragma unroll
            for (int cc = 0; cc < 9; ++cc) {
                bf16x8 a0 = *(const bf16x8*)(Wb + (size_t)cc * 512);
                bf16x8 a1 = *(const bf16x8*)(Wb + (size_t)(9 + cc) * 512);
                bf16x8 b0 = *(const bf16x8*)(Xb + (size_t)cc * 512);
                bf16x8 b1 = *(const bf16x8*)(Xb + (size_t)(9 + cc) * 512);
                acc[0][0] = __builtin_amdgcn_mfma_f32_16x16x32_bf16(a0, b0, acc[0][0], 0, 0, 0);
                acc[0][1] = __builtin_amdgcn_mfma_f32_16x16x32_bf16(a0, b1, acc[0][1], 0, 0, 0);
                acc[1][0] = __builtin_amdgcn_mfma_f32_16x16x32_bf16(a1, b0, acc[1][0], 0, 0, 0);
                acc[1][1] = __builtin_amdgcn_mfma_f32_16x16x32_bf16(a1, b1, acc[1][1], 0, 0, 0);
            }
#pragma unroll
            for (int oi = 0; oi < 2; ++oi)
#pragma unroll
                for (int ji = 0; ji < 2; ++ji)
#pragma unroll
                    for (int r = 0; r < 4; ++r)
                        tr[wv][ji * 16 + lq][oi * 16 + quad * 4 + r]
                            = f2bf(1.4426950408889634f * acc[oi][ji][r]);   // log2(e) pre-scale
            int jl = lane & 31, half = lane >> 5;
            bf16x8 v0 = *(const bf16x8*)&tr[wv][jl][half * 16];
            bf16x8 v1 = *(const bf16x8*)&tr[wv][jl][half * 16 + 8];
            unsigned short* Qm = Qf + ((size_t)(n * MHEAD + m) * HW + jw + jl) * 32 + half * 16;
            *(bf16x8*)Qm = v0;
            *(bf16x8*)(Qm + 8) = v1;
        } else {
            int p0 = (gx - 32) * 128;
            int pw = p0 + wv * 32;
            const unsigned short* XFn = XF + (size_t)n * HW * CDIM;
            size_t bidx[2];
#pragma unroll
            for (int pi = 0; pi < 2; ++pi) {
                int p   = pw + pi * 16 + lq;
                int pos = ((p >> 5) << 7) + ((p & 31) << 1);
                bidx[pi] = ((size_t)(pos >> 4) * 9) * 512 + ((pos & 15) + 16 * quad) * 8;
            }
            const unsigned short* Wkb = WFk + ((size_t)(m * 2) * 9) * 512 + lane * 8;
            const unsigned short* Wvb = WFv + ((size_t)(m * 2) * 9) * 512 + lane * 8;
            f32x4 ak[2][2] = {}, av[2][2] = {};
#pragma unroll
            for (int cc = 0; cc < 9; ++cc) {
                bf16x8 a0k = *(const bf16x8*)(Wkb + (size_t)cc * 512);
                bf16x8 a1k = *(const bf16x8*)(Wkb + (size_t)(9 + cc) * 512);
                bf16x8 a0v = *(const bf16x8*)(Wvb + (size_t)cc * 512);
                bf16x8 a1v = *(const bf16x8*)(Wvb + (size_t)(9 + cc) * 512);
                bf16x8 b0  = *(const bf16x8*)(XFn + bidx[0] + (size_t)cc * 512);
                bf16x8 b1  = *(const bf16x8*)(XFn + bidx[1] + (size_t)cc * 512);
                ak[0][0] = __builtin_amdgcn_mfma_f32_16x16x32_bf16(a0k, b0, ak[0][0], 0, 0, 0);
                ak[0][1] = __builtin_amdgcn_mfma_f32_16x16x32_bf16(a0k, b1, ak[0][1], 0, 0, 0);
                ak[1][0] = __builtin_amdgcn_mfma_f32_16x16x32_bf16(a1k, b0, ak[1][0], 0, 0, 0);
                ak[1][1] = __builtin_amdgcn_mfma_f32_16x16x32_bf16(a1k, b1, ak[1][1], 0, 0, 0);
                av[0][0] = __builtin_amdgcn_mfma_f32_16x16x32_bf16(a0v, b0, av[0][0], 0, 0, 0);
                av[0][1] = __builtin_amdgcn_mfma_f32_16x16x32_bf16(a0v, b1, av[0][1], 0, 0, 0);
                av[1][0] = __builtin_amdgcn_mfma_f32_16x16x32_bf16(a1v, b0, av[1][0], 0, 0, 0);
                av[1][1] = __builtin_amdgcn_mfma_f32_16x16x32_bf16(a1v, b1, av[1][1], 0, 0, 0);
            }
#pragma unroll
            for (int oi = 0; oi < 2; ++oi)
#pragma unroll
                for (int pi = 0; pi < 2; ++pi)
#pragma unroll
                    for (int r = 0; r < 4; ++r)
                        tr[wv][pi * 16 + lq][oi * 16 + quad * 4 + r] = f2bf(ak[oi][pi][r]);
            unsigned short* KFm = KF + (size_t)(n * MHEAD + m) * (PKV * 32);
#pragma unroll
            for (int pi = 0; pi < 2; ++pi) {
                bf16x8 v = *(const bf16x8*)&tr[wv][pi * 16 + lq][quad * 8];
                *(bf16x8*)(KFm + (size_t)((pw >> 4) + pi) * 512 + lane * 8) = v;
            }
#pragma unroll
            for (int oi = 0; oi < 2; ++oi)
#pragma unroll
                for (int pi = 0; pi < 2; ++pi)
#pragma unroll
                    for (int r = 0; r < 4; ++r)
                        tr[wv][oi * 16 + quad * 4 + r][pi * 16 + lq] = f2bf(av[oi][pi][r]);
            unsigned short* VFn = VF + (size_t)n * CDIM * PKV;
#pragma unroll
            for (int oi = 0; oi < 2; ++oi) {
                bf16x8 v = *(const bf16x8*)&tr[wv][oi * 16 + lq][quad * 8];
                *(bf16x8*)(VFn + (size_t)((m * 2 + oi) * 32 + (pw >> 5)) * 512 + lane * 8) = v;
            }
        }
    }
}

// ---------------------------------------------------------------------------
// attn_fused11: round-10 body + final polish:
//  (a) ws rows padded 8->12 floats (48 B, 16B-aligned): the float4 denominator
//      reads were 4-way bank-conflicted (row stride 8 dwords == 8 banks);
//      stride 12 -> ~2-way (free).
//  (b) MIXW (9 floats) preloaded once into spare LDS (offset 48128, inside the
//      unused tr gap) -- removes a post-barrier cold global scalar load from
//      every head's critical path.
__global__ __launch_bounds__(1024, 4) void attn_fused11(
        const unsigned short* __restrict__ Qf, const unsigned short* __restrict__ KF,
        const unsigned short* __restrict__ VF, const unsigned short* __restrict__ WFp,
        const unsigned short* __restrict__ FXb, const unsigned short* __restrict__ FYb,
        const float* __restrict__ MIXW, const float* __restrict__ bproj,
        const float* __restrict__ x, const float* __restrict__ gamma,
        float* __restrict__ OUT) {
    int n    = blockIdx.x >> 7;          // 256 blocks
    int i0   = (blockIdx.x & 127) * 32;  // 32 q-rows per block
    int tid  = threadIdx.x;
    int wv   = tid >> 6;                 // 0..15
    int ti   = wv >> 3;                  // i-tile 0/1
    int w8   = wv & 7;                   // kv-slice
    int lane = tid & 63;
    int lq   = lane & 15;
    int quad = lane >> 4;
    int it0  = i0 + ti * 16;

    int bx_t = (it0 & 63) >> 4;
    int hh   = i0 >> 6;
    int by_t = hh >> 4;
    int dh   = hh & 15;

    // LDS map (within tr's 66048 B):
    //   Rx [2][2][16][82] f32 @ 0       (20992)
    //   Ry [2][2][16][82] f32 @ 20992   (20992)
    //   ws [2][2][16][12] f32 @ 41984   ( 6144)   <- padded rows (was [8])
    //   mixw[9]           f32 @ 48128   (   36)
    //   Mt [32][296]      u16 @ 0       post-loop overlay
    __shared__ __attribute__((aligned(16))) unsigned short tr[32][1032];
    float (*Rx_s)[2][16][82] = reinterpret_cast<float (*)[2][16][82]>((char*)&tr[0][0]);
    float (*Ry_s)[2][16][82] = reinterpret_cast<float (*)[2][16][82]>((char*)&tr[0][0] + 20992);
    float (*ws_s)[2][16][12] = reinterpret_cast<float (*)[2][16][12]>((char*)&tr[0][0] + 41984);
    float* mixw_s            = reinterpret_cast<float*>((char*)&tr[0][0] + 48128);
    unsigned short (*Mt)[296] = reinterpret_cast<unsigned short (*)[296]>(&tr[0][0]);

    float mixed[8][4];
#pragma unroll
    for (int t = 0; t < 8; ++t)
#pragma unroll
        for (int j = 0; j < 4; ++j) mixed[t][j] = 0.f;

    auto r_phase = [&](int mm, bf16x8 af) {
        int pp = mm & 1;
        if (w8 < 5) {
            bf16x8 bR = *(const bf16x8*)(FXb + (size_t)(mm * 8 + bx_t + w8) * 512 + lane * 8);
            f32x4 r = (f32x4){0.f, 0.f, 0.f, 0.f};
            r = __builtin_amdgcn_mfma_f32_16x16x32_bf16(af, bR, r, 0, 0, 0);
#pragma unroll
            for (int reg = 0; reg < 4; ++reg)
                Rx_s[pp][ti][quad * 4 + reg][w8 * 16 + lq] = r[reg];
        } else {
            bf16x8 bR = *(const bf16x8*)(FYb + (size_t)(mm * 8 + by_t + (w8 - 5)) * 512 + lane * 8);
            f32x4 r = (f32x4){0.f, 0.f, 0.f, 0.f};
            r = __builtin_amdgcn_mfma_f32_16x16x32_bf16(af, bR, r, 0, 0, 0);
#pragma unroll
            for (int reg = 0; reg < 4; ++reg)
                Ry_s[pp][ti][quad * 4 + reg][(w8 - 5) * 16 + lq] = r[reg];
        }
        if (w8 < 2) {
            bf16x8 bR = *(const bf16x8*)(FYb + (size_t)(mm * 8 + by_t + 3 + w8) * 512 + lane * 8);
            f32x4 r = (f32x4){0.f, 0.f, 0.f, 0.f};
            r = __builtin_amdgcn_mfma_f32_16x16x32_bf16(af, bR, r, 0, 0, 0);
#pragma unroll
            for (int reg = 0; reg < 4; ++reg)
                Ry_s[pp][ti][quad * 4 + reg][(3 + w8) * 16 + lq] = r[reg];
        }
    };

    if (tid < MHEAD) mixw_s[tid] = MIXW[n * MHEAD + tid];
    bf16x8 af_cur = *(const bf16x8*)(Qf + (((size_t)n * MHEAD) * HW + it0 + lq) * 32 + quad * 8);
    r_phase(0, af_cur);
    __syncthreads();

#pragma unroll 1
    for (int m = 0; m < MHEAD; ++m) {
        const unsigned short* KmF = KF + (size_t)(n * MHEAD + m) * (PKV * 32);
        bf16x8 kf[8];
#pragma unroll
        for (int t = 0; t < 8; ++t)
            kf[t] = *(const bf16x8*)(KmF + (size_t)(w8 * 8 + t) * 512 + lane * 8);

        bf16x8 af_nxt = af_cur;
        __builtin_amdgcn_s_setprio(1);
        if (m + 1 < MHEAD) {
            af_nxt = *(const bf16x8*)(Qf + (((size_t)(n * MHEAD + m + 1)) * HW + it0 + lq) * 32 + quad * 8);
            r_phase(m + 1, af_nxt);
        }
        f32x4 acc[8];
#pragma unroll
        for (int t = 0; t < 8; ++t) {
            f32x4 z = (f32x4){0.f, 0.f, 0.f, 0.f};
            acc[t] = __builtin_amdgcn_mfma_f32_16x16x32_bf16(af_cur, kf[t], z, 0, 0, 0);
        }
        __builtin_amdgcn_s_setprio(0);

        int par = m & 1;
        float exA[4], exB[4];
#pragma unroll
        for (int j = 0; j < 4; ++j) {
            int q = quad * 4 + j;
            exA[j] = Rx_s[par][ti][q][q + 62 - 2 * lq];
            exB[j] = Rx_s[par][ti][q][q + 30 - 2 * lq];
        }
        float rs[4] = {0.f, 0.f, 0.f, 0.f};
#pragma unroll
        for (int tp = 0; tp < 4; ++tp) {
            int u = w8 * 4 + tp;
            float ey[4];
#pragma unroll
            for (int j = 0; j < 4; ++j) ey[j] = Ry_s[par][ti][quad * 4 + j][dh + 62 - 2 * u];
#pragma unroll
            for (int half = 0; half < 2; ++half) {
                int t = tp * 2 + half;
#pragma unroll
                for (int j = 0; j < 4; ++j) {
                    float e = EXP2(acc[t][j] + (half ? exB[j] : exA[j]) + ey[j]);
                    rs[j] += e;
                    acc[t][j] = e;
                }
            }
        }
#pragma unroll
        for (int j = 0; j < 4; ++j) {
            rs[j] += __shfl_xor(rs[j], 1, 64);
            rs[j] += __shfl_xor(rs[j], 2, 64);
            rs[j] += __shfl_xor(rs[j], 4, 64);
            rs[j] += __shfl_xor(rs[j], 8, 64);
        }
        if (lq == 0) {
#pragma unroll
            for (int j = 0; j < 4; ++j) ws_s[par][ti][quad * 4 + j][w8] = rs[j];
        }
        __syncthreads();   // fences ws(m), R(m+1), parity reuse

        {
            float wm = mixw_s[m];
#pragma unroll
            for (int j = 0; j < 4; ++j) {
                int q = quad * 4 + j;
                float4 w0 = *(const float4*)&ws_s[par][ti][q][0];
                float4 w1 = *(const float4*)&ws_s[par][ti][q][4];
                float lt = (w0.x + w0.y) + (w0.z + w0.w) + (w1.x + w1.y) + (w1.z + w1.w);
                float fct = wm / lt;
#pragma unroll
                for (int t = 0; t < 8; ++t) mixed[t][j] += acc[t][j] * fct;
            }
        }
        __builtin_amdgcn_sched_barrier(0);
        af_cur = af_nxt;
    }

    __syncthreads();   // all ws/mixw reads done before tr overlays the region

    // --- P (mixed attn) -> LDS [i (32 rows)][p]
#pragma unroll
    for (int t = 0; t < 8; ++t)
#pragma unroll
        for (int j = 0; j < 4; ++j)
            tr[ti * 16 + quad * 4 + j][w8 * 128 + t * 16 + lq] = f2bf(mixed[t][j]);
    __syncthreads();

    // --- PV: O(32x288) = P(32x1024) @ V^T
    const unsigned short* VFn = VF + (size_t)n * CDIM * PKV;
    f32x4 accpv[2][2];
#pragma unroll
    for (int oi = 0; oi < 2; ++oi)
#pragma unroll
        for (int t2 = 0; t2 < 2; ++t2) accpv[oi][t2] = (f32x4){0.f, 0.f, 0.f, 0.f};
    bool has2 = (wv < 2);
#pragma unroll 4
    for (int pc = 0; pc < 32; ++pc) {
        bf16x8 pf0 = *(const bf16x8*)&tr[lq][pc * 32 + quad * 8];
        bf16x8 pf1 = *(const bf16x8*)&tr[16 + lq][pc * 32 + quad * 8];
        bf16x8 vf0 = *(const bf16x8*)(VFn + (size_t)(wv * 32 + pc) * 512 + lane * 8);
        accpv[0][0] = __builtin_amdgcn_mfma_f32_16x16x32_bf16(pf0, vf0, accpv[0][0], 0, 0, 0);
        accpv[0][1] = __builtin_amdgcn_mfma_f32_16x16x32_bf16(pf1, vf0, accpv[0][1], 0, 0, 0);
        if (has2) {
            bf16x8 vf1 = *(const bf16x8*)(VFn + (size_t)((wv + 16) * 32 + pc) * 512 + lane * 8);
            accpv[1][0] = __builtin_amdgcn_mfma_f32_16x16x32_bf16(pf0, vf1, accpv[1][0], 0, 0, 0);
            accpv[1][1] = __builtin_amdgcn_mfma_f32_16x16x32_bf16(pf1, vf1, accpv[1][1], 0, 0, 0);
        }
    }
    __syncthreads();

#pragma unroll
    for (int oi = 0; oi < 2; ++oi) {
        if (oi == 1 && !has2) continue;
        int ot = wv + oi * 16;
#pragma unroll
        for (int t2 = 0; t2 < 2; ++t2)
#pragma unroll
            for (int r = 0; r < 4; ++r)
                Mt[t2 * 16 + quad * 4 + r][ot * 16 + lq] = f2bf(accpv[oi][t2][r]);
    }
    __syncthreads();

    // --- proj: OUT(288x32) = Wproj @ MID + bias, gamma, residual
    float g = gamma[0];
#pragma unroll
    for (int idx = 0; idx < 3; ++idx) {
        int ot = w8 + idx * 8;
        if (ot >= 18) continue;
        f32x4 acco = (f32x4){0.f, 0.f, 0.f, 0.f};
#pragma unroll
        for (int cc = 0; cc < 9; ++cc) {
            bf16x8 af = *(const bf16x8*)(WFp + (size_t)(ot * 9 + cc) * 512 + lane * 8);
            bf16x8 bfm = *(const bf16x8*)&Mt[ti * 16 + lq][cc * 32 + quad * 8];
            acco = __builtin_amdgcn_mfma_f32_16x16x32_bf16(af, bfm, acco, 0, 0, 0);
        }
#pragma unroll
        for (int r = 0; r < 4; ++r) {
            int o = ot * 16 + quad * 4 + r;
            size_t id = ((size_t)(n * CDIM) + o) * HW + it0 + lq;
            OUT[id] = g * (acco[r] + bproj[o]) + x[id];
        }
    }
}

// ---------------------------------------------------------------------------
extern "C" void kernel_launch(void* const* d_in, const int* in_sizes, int n_in,
                              void* d_out, int out_size, void* d_ws, size_t ws_size,
                              hipStream_t stream) {
    const float* x     = (const float*)d_in[0];
    const float* Wq    = (const float*)d_in[1];
    const float* Wk    = (const float*)d_in[2];
    const float* Wv    = (const float*)d_in[3];
    const float* Wx    = (const float*)d_in[4];
    const float* Wy    = (const float*)d_in[5];
    const float* Wproj = (const float*)d_in[6];
    const float* bproj = (const float*)d_in[7];
    const float* Wc    = (const float*)d_in[8];
    const float* bc    = (const float*)d_in[9];
    const float* gamma = (const float*)d_in[10];
    float* out = (float*)d_out;

    float* ws = (float*)d_ws;
    size_t off = 0;
    unsigned short* Qf  = (unsigned short*)(ws + off); off += (size_t)NB * MHEAD * HW * 32 / 2;
    unsigned short* KF  = (unsigned short*)(ws + off); off += (size_t)NB * MHEAD * PKV * 32 / 2;
    unsigned short* VF  = (unsigned short*)(ws + off); off += (size_t)NB * CDIM * PKV / 2;
    unsigned short* WFq = (unsigned short*)(ws + off); off += (size_t)CDIM * CDIM / 2;
    unsigned short* WFk = (unsigned short*)(ws + off); off += (size_t)CDIM * CDIM / 2;
    unsigned short* WFv = (unsigned short*)(ws + off); off += (size_t)CDIM * CDIM / 2;
    unsigned short* WFp = (unsigned short*)(ws + off); off += (size_t)CDIM * CDIM / 2;
    unsigned short* XF  = (unsigned short*)(ws + off); off += (size_t)NB * HW * CDIM / 2;
    unsigned short* FXb = (unsigned short*)(ws + off); off += (size_t)MHEAD * 8 * 512 / 2;
    unsigned short* FYb = (unsigned short*)(ws + off); off += (size_t)MHEAD * 8 * 512 / 2;
    float* MXP  = ws + off; off += (size_t)NB * CDIM * 32;
    float* MIXW = ws + off; off += 32;

    prep<<<991, 256, 0, stream>>>(x, Wq, Wk, Wv, Wproj, Wx, Wy,
                                  XF, WFq, WFk, WFv, WFp, FXb, FYb, MXP);
    mid<<<721, 256, 0, stream>>>(Wq, MXP, Wc, bc, MIXW,
                                 WFq, WFk, WFv, XF, Qf, KF, VF);
    attn_fused11<<<NB * HW / 32, 1024, 0, stream>>>(Qf, KF, VF, WFp, FXb, FYb, MIXW,
                                                    bproj, x, gamma, out);
}